// Round 5
// baseline (351.449 us; speedup 1.0000x reference)
//
#include <hip/hip_runtime.h>
#include <hip/hip_fp16.h>

#define NN 50000
#define NGROUP 3125   // NN / 16 (exact)
#define NCHUNK 391    // ceil(NN / 128)
#define CHCAP 3072    // bucket capacity per chunk (expected ~2046)
#define SLAB 8192
#define NREP 8        // stats atomic replication factor
#define BN_EPS 1e-5f

typedef unsigned int uint;
typedef unsigned short ushort;
typedef _Float16 half8 __attribute__((ext_vector_type(8)));
typedef _Float16 half2t __attribute__((ext_vector_type(2)));
typedef float floatx4 __attribute__((ext_vector_type(4)));

__device__ __forceinline__ int aswz(int slot) { return slot ^ ((slot >> 4) & 7); }

__device__ __forceinline__ float h_lo(uint u) {
    return __half2float(__ushort_as_half((ushort)(u & 0xFFFFu)));
}
__device__ __forceinline__ float h_hi(uint u) {
    return __half2float(__ushort_as_half((ushort)(u >> 16)));
}
__device__ __forceinline__ void unpack8(uint4 v, float* f) {
    f[0] = h_lo(v.x); f[1] = h_hi(v.x);
    f[2] = h_lo(v.y); f[3] = h_hi(v.y);
    f[4] = h_lo(v.z); f[5] = h_hi(v.z);
    f[6] = h_lo(v.w); f[7] = h_hi(v.w);
}
// packed fp16 add: 2 channels per op (v_pk_add_f16)
__device__ __forceinline__ uint pkadd(uint a, uint b) {
    half2t x = __builtin_bit_cast(half2t, a);
    half2t y = __builtin_bit_cast(half2t, b);
    half2t r = x + y;
    return __builtin_bit_cast(uint, r);
}
__device__ __forceinline__ void pkadd4(uint4& a, uint4 b) {
    a.x = pkadd(a.x, b.x); a.y = pkadd(a.y, b.y);
    a.z = pkadd(a.z, b.z); a.w = pkadd(a.w, b.w);
}

// ================= CSR build: LDS-sorted buckets, chunk-local fills (round-0 proven) =========
__global__ __launch_bounds__(256) void sortA_kernel(
    const int* __restrict__ ei, int* __restrict__ gcur,
    uint* __restrict__ bucket, int E)
{
    __shared__ int s_hist[NCHUNK];
    __shared__ int s_offs[NCHUNK];
    __shared__ int s_cur[NCHUNK];
    __shared__ int s_gb[NCHUNK];
    __shared__ int s_scanA[512], s_scanB[512];
    __shared__ uint s_sorted[SLAB];

    const int tid  = threadIdx.x;
    const int base = blockIdx.x * SLAB;
    const int cnt  = min(SLAB, E - base);

    for (int i = tid; i < NCHUNK; i += 256) s_hist[i] = 0;
    __syncthreads();

    uint pk[SLAB / 256];
    int nloc = 0;
    for (int i = tid; i < cnt; i += 256) {
        int src = ei[base + i];
        int dst = ei[E + base + i];
        int c = dst >> 7;
        pk[nloc++] = (uint)src | ((uint)(dst & 127) << 16) | ((uint)c << 23);
        atomicAdd(&s_hist[c], 1);
    }
    __syncthreads();
    for (int i = tid; i < 512; i += 256) s_scanA[i] = (i < NCHUNK) ? s_hist[i] : 0;
    __syncthreads();
    int* sa = s_scanA; int* sb = s_scanB;
    for (int off = 1; off < 512; off <<= 1) {
        for (int i = tid; i < 512; i += 256)
            sb[i] = sa[i] + ((i >= off) ? sa[i - off] : 0);
        __syncthreads();
        int* t = sa; sa = sb; sb = t;
    }
    for (int i = tid; i < NCHUNK; i += 256) {
        int excl = sa[i] - s_hist[i];
        s_offs[i] = excl;
        s_cur[i]  = excl;
    }
    __syncthreads();
    for (int k = 0; k < nloc; k++) {
        int c = pk[k] >> 23;
        int pos = atomicAdd(&s_cur[c], 1);
        s_sorted[pos] = pk[k];
    }
    __syncthreads();
    for (int c = tid; c < NCHUNK; c += 256) {
        int n = s_hist[c];
        s_gb[c] = n ? atomicAdd(&gcur[c], n) : 0;
    }
    __syncthreads();
    for (int i = tid; i < cnt; i += 256) {
        uint v = s_sorted[i];
        int c = v >> 23;
        int li = i - s_offs[c];
        bucket[(size_t)c * CHCAP + s_gb[c] + li] = v;
    }
}

// phase B: one block per chunk — inline base scan + per-row hist/scan -> rowPtr + dense fill.
__global__ __launch_bounds__(256) void fillB_kernel(
    const uint* __restrict__ bucket, const int* __restrict__ gcur,
    int* __restrict__ rowPtr, int* __restrict__ csr_src)
{
    __shared__ int s_hist[128];
    __shared__ int s_excl[128];
    __shared__ int s_cur[128];
    __shared__ int s_ws[4];
    __shared__ int s_base;
    const int c = blockIdx.x;
    const int tid = threadIdx.x;
    const int cnt = gcur[c];
    const int row0 = c * 128;

    int part = 0;
    for (int i = tid; i < c; i += 256) part += gcur[i];
    #pragma unroll
    for (int off = 32; off >= 1; off >>= 1) part += __shfl_down(part, off, 64);
    if ((tid & 63) == 0) s_ws[tid >> 6] = part;
    if (tid < 128) s_hist[tid] = 0;
    __syncthreads();
    if (tid == 0) s_base = s_ws[0] + s_ws[1] + s_ws[2] + s_ws[3];
    __syncthreads();
    const int base = s_base;
    if (tid == 0 && c == NCHUNK - 1) rowPtr[NN] = base + cnt;

    for (int i = tid; i < cnt; i += 256) {
        uint v = bucket[(size_t)c * CHCAP + i];
        atomicAdd(&s_hist[(v >> 16) & 127], 1);
    }
    __syncthreads();
    if (tid < 128) {
        int lane = tid & 63;
        int v = s_hist[tid];
        int incl = v;
        #pragma unroll
        for (int off = 1; off < 64; off <<= 1) {
            int t = __shfl_up(incl, off, 64);
            if (lane >= off) incl += t;
        }
        s_excl[tid] = incl - v;
    }
    __syncthreads();
    if (tid < 128) {
        int excl = s_excl[tid];
        if (tid >= 64) excl += s_excl[63] + s_hist[63];
        s_cur[tid] = excl;
        int row = row0 + tid;
        if (row < NN) rowPtr[row] = base + excl;
    }
    __syncthreads();
    for (int i = tid; i < cnt; i += 256) {
        uint v = bucket[(size_t)c * CHCAP + i];
        int dl  = (v >> 16) & 127;
        int src = v & 0xFFFFu;
        int ofs = atomicAdd(&s_cur[dl], 1);
        csr_src[base + ofs] = src;
    }
}

// ======== proj: y = W_a^T * z, z = BNReLU(h_in) [APPLY] or cvt(x) [layer 1] ========
template<int FIN, bool APPLY>
__global__ __launch_bounds__(256, 4) void proj_kernel(
    const void* __restrict__ in_v,
    const float* __restrict__ stats_in, const float* __restrict__ g_in,
    const float* __restrict__ be_in,
    const float* __restrict__ wa,
    ushort* __restrict__ y_out)
{
    constexpr int KC = FIN / 32;
    __shared__ __align__(16) _Float16 s_B[FIN * 64];
    __shared__ __align__(16) _Float16 s_Y[4][1024];

    const int tid = threadIdx.x, w = tid >> 6, lane = tid & 63;
    const int q = lane >> 4, mm = lane & 15;

    for (int i = tid; i < FIN * 64; i += 256) {
        int j = i & 7, l = (i >> 3) & 63, t = i >> 9;
        int kc = t >> 2, nt = t & 3;
        int k = kc * 32 + (l >> 4) * 8 + j;
        int n = nt * 16 + (l & 15);
        s_B[i] = (_Float16)wa[k * 64 + n];
    }

    float scv[2][8], shv[2][8];
    if (APPLY) {
        #pragma unroll
        for (int kc = 0; kc < 2; kc++)
            #pragma unroll
            for (int j = 0; j < 8; j++) {
                int c = kc * 32 + q * 8 + j;
                float s0 = 0.f, s1 = 0.f;
                #pragma unroll
                for (int r = 0; r < NREP; r++) {
                    s0 += stats_in[r * 128 + c];
                    s1 += stats_in[r * 128 + 64 + c];
                }
                float mean = s0 * (1.0f / NN);
                float var  = s1 * (1.0f / NN) - mean * mean;
                float rstd = rsqrtf(var + BN_EPS);
                float s    = rstd * g_in[c];
                scv[kc][j] = s;
                shv[kc][j] = be_in[c] - mean * s;
            }
    }
    __syncthreads();

    int g = blockIdx.x * 4 + w;
    if (g >= NGROUP) return;
    const int row = g * 16 + mm;

    half8 af[KC];
    if (FIN == 128) {
        const float* xin = (const float*)in_v;
        #pragma unroll
        for (int kc = 0; kc < KC; kc++) {
            const float* p = xin + (size_t)row * 128 + kc * 32 + q * 8;
            float4 a = *(const float4*)p;
            float4 b = *(const float4*)(p + 4);
            half8 hv;
            hv[0] = (_Float16)a.x; hv[1] = (_Float16)a.y;
            hv[2] = (_Float16)a.z; hv[3] = (_Float16)a.w;
            hv[4] = (_Float16)b.x; hv[5] = (_Float16)b.y;
            hv[6] = (_Float16)b.z; hv[7] = (_Float16)b.w;
            af[kc] = hv;
        }
    } else {
        const ushort* hin = (const ushort*)in_v;
        #pragma unroll
        for (int kc = 0; kc < KC; kc++) {
            uint4 vv = *(const uint4*)(hin + (size_t)row * 64 + kc * 32 + q * 8);
            float f[8]; unpack8(vv, f);
            half8 hv;
            #pragma unroll
            for (int j = 0; j < 8; j++) {
                float z = APPLY ? fmaxf(fmaf(f[j], scv[kc][j], shv[kc][j]), 0.0f) : f[j];
                hv[j] = (_Float16)z;
            }
            af[kc] = hv;
        }
    }

    floatx4 acc[4] = {};
    #pragma unroll
    for (int nt = 0; nt < 4; nt++)
        #pragma unroll
        for (int kc = 0; kc < KC; kc++) {
            half8 bf = *(const half8*)(s_B + ((size_t)(kc * 4 + nt) * 64 + lane) * 8);
            acc[nt] = __builtin_amdgcn_mfma_f32_16x16x32_f16(af[kc], bf, acc[nt], 0, 0, 0);
        }

    _Float16* s_Yw = &s_Y[w][0];
    #pragma unroll
    for (int nt = 0; nt < 4; nt++)
        #pragma unroll
        for (int r = 0; r < 4; r++)
            s_Yw[(q * 4 + r) * 64 + nt * 16 + mm] = (_Float16)acc[nt][r];
    half8 t0 = *(const half8*)(s_Yw + lane * 8);
    half8 t1 = *(const half8*)(s_Yw + 512 + lane * 8);
    half8* dst = (half8*)((_Float16*)y_out + (size_t)g * 1024);
    dst[lane] = t0;
    dst[64 + lane] = t1;
}

// ======== gather (round-0 structure): 1 wave per 16-row group; 4-row batches;
// NEW: edge-unrolled x2 (4 in-flight y4 loads per row instead of 2) + packed fp16
// accumulation to keep the live set under the 128-VGPR cap. ========
__global__ __launch_bounds__(512, 4) void gin_gather_kernel(
    const ushort* __restrict__ y,
    const int* __restrict__ rowPtr, const int* __restrict__ csr_src,
    const float* __restrict__ eps_p, const float* __restrict__ ba,
    const float* __restrict__ wb, const float* __restrict__ bb,
    ushort* __restrict__ h_out, float* __restrict__ stats_out)
{
    __shared__ __align__(16) _Float16 s_B2[64 * 64];
    __shared__ __align__(16) _Float16 s_A[8][1024];
    __shared__ float s_red[8][64];

    const int tid = threadIdx.x, w = tid >> 6, lane = tid & 63;
    const int cc = lane & 7, gph = lane >> 3;
    const int q = lane >> 4, mm = lane & 15;

    for (int i = tid; i < 64 * 64; i += 512) {
        int j = i & 7, l = (i >> 3) & 63, t = i >> 9;
        int kc = t >> 2, nt = t & 3;
        int k = kc * 32 + (l >> 4) * 8 + j;
        int n = nt * 16 + (l & 15);
        s_B2[i] = (_Float16)wb[k * 64 + n];
    }

    const float eps1 = 1.0f + eps_p[0];
    float bav[8];
    #pragma unroll
    for (int j = 0; j < 8; j++) bav[j] = ba[8 * cc + j];
    float bbv[4];
    #pragma unroll
    for (int nt = 0; nt < 4; nt++) bbv[nt] = bb[nt * 16 + mm];
    __syncthreads();

    float bn_s[4] = {0.f, 0.f, 0.f, 0.f};
    float bn_q[4] = {0.f, 0.f, 0.f, 0.f};
    const uint4* y4 = (const uint4*)y;
    const int g = blockIdx.x * 8 + w;

    if (g < NGROUP) {
        const int row0 = g * 16;
        _Float16* s_Aw = &s_A[w][0];

        for (int m = 0; m < 16; m += 4) {
            int e[4], en[4], s0[4], s1[4];
            uint4 v0[4], v1[4];
            uint4 pk[4];
            #pragma unroll
            for (int i = 0; i < 4; i++) {
                int row = row0 + m + i;
                e[i] = rowPtr[row] + gph;
                en[i] = rowPtr[row + 1];
                pk[i].x = pk[i].y = pk[i].z = pk[i].w = 0u;
            }
            #pragma unroll
            for (int i = 0; i < 4; i++) s0[i] = (e[i] < en[i]) ? csr_src[e[i]] : -1;
            #pragma unroll
            for (int i = 0; i < 4; i++) s1[i] = (e[i] + 8 < en[i]) ? csr_src[e[i] + 8] : -1;
            #pragma unroll
            for (int i = 0; i < 4; i++) if (s0[i] >= 0) v0[i] = y4[(size_t)s0[i] * 8 + cc];
            #pragma unroll
            for (int i = 0; i < 4; i++) if (s1[i] >= 0) v1[i] = y4[(size_t)s1[i] * 8 + cc];

            int mx = max(max(max(s0[0], s0[1]), max(s0[2], s0[3])),
                         max(max(s1[0], s1[1]), max(s1[2], s1[3])));
            while (mx >= 0) {
                int n0[4], n1[4]; uint4 p0[4], p1[4];
                #pragma unroll
                for (int i = 0; i < 4; i++) n0[i] = (e[i] + 16 < en[i]) ? csr_src[e[i] + 16] : -1;
                #pragma unroll
                for (int i = 0; i < 4; i++) n1[i] = (e[i] + 24 < en[i]) ? csr_src[e[i] + 24] : -1;
                #pragma unroll
                for (int i = 0; i < 4; i++) if (n0[i] >= 0) p0[i] = y4[(size_t)n0[i] * 8 + cc];
                #pragma unroll
                for (int i = 0; i < 4; i++) if (n1[i] >= 0) p1[i] = y4[(size_t)n1[i] * 8 + cc];
                #pragma unroll
                for (int i = 0; i < 4; i++) {
                    if (s0[i] >= 0) pkadd4(pk[i], v0[i]);
                    if (s1[i] >= 0) pkadd4(pk[i], v1[i]);
                    e[i] += 16;
                    s0[i] = n0[i]; v0[i] = p0[i];
                    s1[i] = n1[i]; v1[i] = p1[i];
                }
                mx = max(max(max(s0[0], s0[1]), max(s0[2], s0[3])),
                         max(max(s1[0], s1[1]), max(s1[2], s1[3])));
            }

            // flush one row at a time (keeps peak register pressure low)
            #pragma unroll
            for (int i = 0; i < 4; i++) {
                float a[8];
                unpack8(pk[i], a);
                if (gph == 0) {
                    uint4 sv = y4[(size_t)(row0 + m + i) * 8 + cc];
                    float f[8]; unpack8(sv, f);
                    #pragma unroll
                    for (int j = 0; j < 8; j++) a[j] = fmaf(eps1, f[j], a[j]);
                }
                #pragma unroll
                for (int off = 8; off < 64; off <<= 1)
                    #pragma unroll
                    for (int j = 0; j < 8; j++)
                        a[j] += __shfl_xor(a[j], off, 64);
                if (gph == 0) {
                    half8 hv;
                    #pragma unroll
                    for (int j = 0; j < 8; j++)
                        hv[j] = (_Float16)fmaxf(a[j] + bav[j], 0.0f);
                    int slot = (cc >> 2) * 64 + (cc & 3) * 16 + (m + i);
                    *(half8*)(s_Aw + (size_t)aswz(slot) * 8) = hv;
                }
            }
        }

        half8 af2[2];
        #pragma unroll
        for (int kc = 0; kc < 2; kc++)
            af2[kc] = *(const half8*)(s_Aw + (size_t)aswz(kc * 64 + lane) * 8);
        floatx4 acc2[4] = {};
        #pragma unroll
        for (int nt = 0; nt < 4; nt++)
            #pragma unroll
            for (int kc = 0; kc < 2; kc++) {
                half8 bf = *(const half8*)(s_B2 + ((size_t)(kc * 4 + nt) * 64 + lane) * 8);
                acc2[nt] = __builtin_amdgcn_mfma_f32_16x16x32_f16(af2[kc], bf, acc2[nt], 0, 0, 0);
            }

        #pragma unroll
        for (int nt = 0; nt < 4; nt++)
            #pragma unroll
            for (int r = 0; r < 4; r++) {
                float val = fmaxf(acc2[nt][r] + bbv[nt], 0.0f);
                bn_s[nt] += val;
                bn_q[nt] += val * val;
                s_Aw[(q * 4 + r) * 64 + nt * 16 + mm] = (_Float16)val;
            }
        half8 t0 = *(const half8*)(s_Aw + lane * 8);
        half8 t1 = *(const half8*)(s_Aw + 512 + lane * 8);
        half8* dst = (half8*)((_Float16*)h_out + (size_t)row0 * 64);
        dst[lane] = t0;
        dst[64 + lane] = t1;
    }

    #pragma unroll
    for (int nt = 0; nt < 4; nt++) {
        bn_s[nt] += __shfl_xor(bn_s[nt], 16, 64);
        bn_s[nt] += __shfl_xor(bn_s[nt], 32, 64);
        bn_q[nt] += __shfl_xor(bn_q[nt], 16, 64);
        bn_q[nt] += __shfl_xor(bn_q[nt], 32, 64);
    }
    __syncthreads();
    if (lane < 16) {
        #pragma unroll
        for (int nt = 0; nt < 4; nt++) s_red[w][nt * 16 + lane] = bn_s[nt];
    }
    __syncthreads();
    if (w == 0) {
        float s = 0;
        #pragma unroll
        for (int j = 0; j < 8; j++) s += s_red[j][lane];
        atomicAdd(&stats_out[(size_t)(blockIdx.x & (NREP - 1)) * 128 + lane], s);
    }
    __syncthreads();
    if (lane < 16) {
        #pragma unroll
        for (int nt = 0; nt < 4; nt++) s_red[w][nt * 16 + lane] = bn_q[nt];
    }
    __syncthreads();
    if (w == 0) {
        float s = 0;
        #pragma unroll
        for (int j = 0; j < 8; j++) s += s_red[j][lane];
        atomicAdd(&stats_out[(size_t)(blockIdx.x & (NREP - 1)) * 128 + 64 + lane], s);
    }
}

// ---------------- final: BN+ReLU of layer 3 (fp16 h), then (N,64)@(64,10)+b ----------------
__global__ __launch_bounds__(256) void final_linear_kernel(
    const ushort* __restrict__ h, const float* __restrict__ stats,
    const float* __restrict__ g, const float* __restrict__ be,
    const float* __restrict__ w, const float* __restrict__ b,
    float* __restrict__ out)
{
    __shared__ float s_w[640];
    __shared__ float s_b[10];
    __shared__ float s_scale[64];
    __shared__ float s_shift[64];
    for (int i = threadIdx.x; i < 640; i += 256) s_w[i] = w[i];
    if (threadIdx.x < 10) s_b[threadIdx.x] = b[threadIdx.x];
    if (threadIdx.x < 64) {
        int c = threadIdx.x;
        float s0 = 0.f, s1 = 0.f;
        #pragma unroll
        for (int r = 0; r < NREP; r++) {
            s0 += stats[r * 128 + c];
            s1 += stats[r * 128 + 64 + c];
        }
        float mean = s0 * (1.0f / NN);
        float var  = s1 * (1.0f / NN) - mean * mean;
        float rstd = rsqrtf(var + BN_EPS);
        float s    = rstd * g[c];
        s_scale[c] = s;
        s_shift[c] = be[c] - mean * s;
    }
    __syncthreads();
    int row = blockIdx.x * 256 + threadIdx.x;
    if (row >= NN) return;
    float acc[10];
    #pragma unroll
    for (int c = 0; c < 10; c++) acc[c] = s_b[c];
    const uint4* hr = (const uint4*)(h + (size_t)row * 64);
    #pragma unroll
    for (int ch = 0; ch < 8; ch++) {
        uint4 v = hr[ch];
        float f[8]; unpack8(v, f);
        #pragma unroll
        for (int j = 0; j < 8; j++) {
            int k = ch * 8 + j;
            float val = fmaxf(fmaf(f[j], s_scale[k], s_shift[k]), 0.0f);
            #pragma unroll
            for (int c = 0; c < 10; c++) acc[c] = fmaf(val, s_w[k * 10 + c], acc[c]);
        }
    }
    #pragma unroll
    for (int c = 0; c < 10; c++) out[row * 10 + c] = acc[c];
}

extern "C" void kernel_launch(void* const* d_in, const int* in_sizes, int n_in,
                              void* d_out, int out_size, void* d_ws, size_t ws_size,
                              hipStream_t stream)
{
    const float* x  = (const float*)d_in[0];
    const int*   ei = (const int*)d_in[1];
    const int E = in_sizes[1] / 2;

    const float* eps[3]; const float* wa[3]; const float* ba[3];
    const float* wb[3];  const float* bb[3]; const float* g[3]; const float* be[3];
    for (int i = 0; i < 3; i++) {
        int base = 2 + 7 * i;
        eps[i] = (const float*)d_in[base + 0];
        wa[i]  = (const float*)d_in[base + 1];
        ba[i]  = (const float*)d_in[base + 2];
        wb[i]  = (const float*)d_in[base + 3];
        bb[i]  = (const float*)d_in[base + 4];
        g[i]   = (const float*)d_in[base + 5];
        be[i]  = (const float*)d_in[base + 6];
    }
    const float* lin_w = (const float*)d_in[23];
    const float* lin_b = (const float*)d_in[24];
    float* out = (float*)d_out;

    // workspace layout: gcur and stats adjacent -> single zeroing memset
    char*  base   = (char*)d_ws;
    int*   gcur   = (int*)base;               // 512 ints
    float* stats  = (float*)(gcur + 512);     // 3 layers x NREP x 128 floats
    int*   rowPtr = (int*)(stats + 3 * NREP * 128);  // NN+1
    uint*  bucket = (uint*)(rowPtr + NN + 1); // NCHUNK*CHCAP
    int*   csrsrc = (int*)(bucket + (size_t)NCHUNK * CHCAP);  // E
    size_t ioff   = (char*)(csrsrc + E) - base;
    ushort* yb    = (ushort*)(base + ((ioff + 15) & ~(size_t)15));  // NN*64
    ushort* hA    = yb + (size_t)NN * 64;     // NN*64
    ushort* hB    = hA + (size_t)NN * 64;     // NN*64

    // ---- CSR build (bucketed) ----
    hipMemsetAsync(gcur, 0, (512 + 3 * NREP * 128) * sizeof(int), stream);
    sortA_kernel<<<(E + SLAB - 1) / SLAB, 256, 0, stream>>>(ei, gcur, bucket, E);
    fillB_kernel<<<NCHUNK, 256, 0, stream>>>(bucket, gcur, rowPtr, csrsrc);

    const int PB = (NGROUP + 3) / 4;   // 782 proj blocks
    const int GB = (NGROUP + 7) / 8;   // 391 gather blocks (1 wave per group)

    // ---- layer 1: proj x (fp32,128) -> y; fused gather+MLP ----
    proj_kernel<128, false><<<PB, 256, 0, stream>>>(
        x, nullptr, nullptr, nullptr, wa[0], yb);
    gin_gather_kernel<<<GB, 512, 0, stream>>>(
        yb, rowPtr, csrsrc, eps[0], ba[0], wb[0], bb[0], hA, stats);
    // ---- layer 2 ----
    proj_kernel<64, true><<<PB, 256, 0, stream>>>(
        hA, stats, g[0], be[0], wa[1], yb);
    gin_gather_kernel<<<GB, 512, 0, stream>>>(
        yb, rowPtr, csrsrc, eps[1], ba[1], wb[1], bb[1], hB, stats + NREP * 128);
    // ---- layer 3 ----
    proj_kernel<64, true><<<PB, 256, 0, stream>>>(
        hB, stats + NREP * 128, g[1], be[1], wa[2], yb);
    gin_gather_kernel<<<GB, 512, 0, stream>>>(
        yb, rowPtr, csrsrc, eps[2], ba[2], wb[2], bb[2], hA, stats + 2 * NREP * 128);
    // ---- final ----
    final_linear_kernel<<<(NN + 255) / 256, 256, 0, stream>>>(
        hA, stats + 2 * NREP * 128, g[2], be[2], lin_w, lin_b, out);
}

// Round 6
// 322.601 us; speedup vs baseline: 1.0894x; 1.0894x over previous
//
#include <hip/hip_runtime.h>
#include <hip/hip_fp16.h>

#define NN 50000
#define NGROUP 3125   // NN / 16 (exact)
#define NCHUNK 391    // ceil(NN / 128)
#define CHCAP 3072    // bucket capacity per chunk (expected ~2046)
#define SLAB 8192
#define NREP 8        // stats atomic replication factor
#define BN_EPS 1e-5f

typedef unsigned int uint;
typedef unsigned short ushort;
typedef _Float16 half8 __attribute__((ext_vector_type(8)));
typedef _Float16 half2t __attribute__((ext_vector_type(2)));
typedef float floatx4 __attribute__((ext_vector_type(4)));

__device__ __forceinline__ int aswz(int slot) { return slot ^ ((slot >> 4) & 7); }

__device__ __forceinline__ float h_lo(uint u) {
    return __half2float(__ushort_as_half((ushort)(u & 0xFFFFu)));
}
__device__ __forceinline__ float h_hi(uint u) {
    return __half2float(__ushort_as_half((ushort)(u >> 16)));
}
__device__ __forceinline__ void unpack8(uint4 v, float* f) {
    f[0] = h_lo(v.x); f[1] = h_hi(v.x);
    f[2] = h_lo(v.y); f[3] = h_hi(v.y);
    f[4] = h_lo(v.z); f[5] = h_hi(v.z);
    f[6] = h_lo(v.w); f[7] = h_hi(v.w);
}
// packed fp16 add: 2 channels per op (v_pk_add_f16)
__device__ __forceinline__ uint pkadd(uint a, uint b) {
    half2t x = __builtin_bit_cast(half2t, a);
    half2t y = __builtin_bit_cast(half2t, b);
    half2t r = x + y;
    return __builtin_bit_cast(uint, r);
}
__device__ __forceinline__ void pkadd4(uint4& a, uint4 b) {
    a.x = pkadd(a.x, b.x); a.y = pkadd(a.y, b.y);
    a.z = pkadd(a.z, b.z); a.w = pkadd(a.w, b.w);
}

// ================= CSR build: LDS-sorted buckets (round-0 proven) =================
__global__ __launch_bounds__(256) void sortA_kernel(
    const int* __restrict__ ei, int* __restrict__ gcur,
    uint* __restrict__ bucket, int E)
{
    __shared__ int s_hist[NCHUNK];
    __shared__ int s_offs[NCHUNK];
    __shared__ int s_cur[NCHUNK];
    __shared__ int s_gb[NCHUNK];
    __shared__ int s_scanA[512], s_scanB[512];
    __shared__ uint s_sorted[SLAB];

    const int tid  = threadIdx.x;
    const int base = blockIdx.x * SLAB;
    const int cnt  = min(SLAB, E - base);

    for (int i = tid; i < NCHUNK; i += 256) s_hist[i] = 0;
    __syncthreads();

    uint pk[SLAB / 256];
    int nloc = 0;
    for (int i = tid; i < cnt; i += 256) {
        int src = ei[base + i];
        int dst = ei[E + base + i];
        int c = dst >> 7;
        pk[nloc++] = (uint)src | ((uint)(dst & 127) << 16) | ((uint)c << 23);
        atomicAdd(&s_hist[c], 1);
    }
    __syncthreads();
    for (int i = tid; i < 512; i += 256) s_scanA[i] = (i < NCHUNK) ? s_hist[i] : 0;
    __syncthreads();
    int* sa = s_scanA; int* sb = s_scanB;
    for (int off = 1; off < 512; off <<= 1) {
        for (int i = tid; i < 512; i += 256)
            sb[i] = sa[i] + ((i >= off) ? sa[i - off] : 0);
        __syncthreads();
        int* t = sa; sa = sb; sb = t;
    }
    for (int i = tid; i < NCHUNK; i += 256) {
        int excl = sa[i] - s_hist[i];
        s_offs[i] = excl;
        s_cur[i]  = excl;
    }
    __syncthreads();
    for (int k = 0; k < nloc; k++) {
        int c = pk[k] >> 23;
        int pos = atomicAdd(&s_cur[c], 1);
        s_sorted[pos] = pk[k];
    }
    __syncthreads();
    for (int c = tid; c < NCHUNK; c += 256) {
        int n = s_hist[c];
        s_gb[c] = n ? atomicAdd(&gcur[c], n) : 0;
    }
    __syncthreads();
    for (int i = tid; i < cnt; i += 256) {
        uint v = s_sorted[i];
        int c = v >> 23;
        int li = i - s_offs[c];
        bucket[(size_t)c * CHCAP + s_gb[c] + li] = v;
    }
}

// phase B: one block per chunk — inline base scan + per-row hist/scan -> rowPtr + dense fill.
__global__ __launch_bounds__(256) void fillB_kernel(
    const uint* __restrict__ bucket, const int* __restrict__ gcur,
    int* __restrict__ rowPtr, int* __restrict__ csr_src)
{
    __shared__ int s_hist[128];
    __shared__ int s_excl[128];
    __shared__ int s_cur[128];
    __shared__ int s_ws[4];
    __shared__ int s_base;
    const int c = blockIdx.x;
    const int tid = threadIdx.x;
    const int cnt = gcur[c];
    const int row0 = c * 128;

    int part = 0;
    for (int i = tid; i < c; i += 256) part += gcur[i];
    #pragma unroll
    for (int off = 32; off >= 1; off >>= 1) part += __shfl_down(part, off, 64);
    if ((tid & 63) == 0) s_ws[tid >> 6] = part;
    if (tid < 128) s_hist[tid] = 0;
    __syncthreads();
    if (tid == 0) s_base = s_ws[0] + s_ws[1] + s_ws[2] + s_ws[3];
    __syncthreads();
    const int base = s_base;
    if (tid == 0 && c == NCHUNK - 1) rowPtr[NN] = base + cnt;

    for (int i = tid; i < cnt; i += 256) {
        uint v = bucket[(size_t)c * CHCAP + i];
        atomicAdd(&s_hist[(v >> 16) & 127], 1);
    }
    __syncthreads();
    if (tid < 128) {
        int lane = tid & 63;
        int v = s_hist[tid];
        int incl = v;
        #pragma unroll
        for (int off = 1; off < 64; off <<= 1) {
            int t = __shfl_up(incl, off, 64);
            if (lane >= off) incl += t;
        }
        s_excl[tid] = incl - v;
    }
    __syncthreads();
    if (tid < 128) {
        int excl = s_excl[tid];
        if (tid >= 64) excl += s_excl[63] + s_hist[63];
        s_cur[tid] = excl;
        int row = row0 + tid;
        if (row < NN) rowPtr[row] = base + excl;
    }
    __syncthreads();
    for (int i = tid; i < cnt; i += 256) {
        uint v = bucket[(size_t)c * CHCAP + i];
        int dl  = (v >> 16) & 127;
        int src = v & 0xFFFFu;
        int ofs = atomicAdd(&s_cur[dl], 1);
        csr_src[base + ofs] = src;
    }
}

// ======== proj: y = W_a^T * z, z = BNReLU(h_in) [APPLY] or cvt(x) [layer 1] ========
// Side job: blocks 0..7 pre-pack this layer's wb into fp16 gather layout (wbh).
template<int FIN, bool APPLY>
__global__ __launch_bounds__(256, 4) void proj_kernel(
    const void* __restrict__ in_v,
    const float* __restrict__ stats_in, const float* __restrict__ g_in,
    const float* __restrict__ be_in,
    const float* __restrict__ wa,
    const float* __restrict__ wb_src, _Float16* __restrict__ wbh_out,
    ushort* __restrict__ y_out)
{
    constexpr int KC = FIN / 32;
    __shared__ __align__(16) _Float16 s_B[FIN * 64];
    __shared__ __align__(16) _Float16 s_Y[4][1024];

    const int tid = threadIdx.x, w = tid >> 6, lane = tid & 63;
    const int q = lane >> 4, mm = lane & 15;

    if (blockIdx.x < 8) {
        for (int t = tid; t < 512; t += 256) {
            int i = blockIdx.x * 512 + t;
            int j = i & 7, l = (i >> 3) & 63, tt = i >> 9;
            int kc = tt >> 2, nt = tt & 3;
            int k = kc * 32 + (l >> 4) * 8 + j;
            int n = nt * 16 + (l & 15);
            wbh_out[i] = (_Float16)wb_src[k * 64 + n];
        }
    }

    for (int i = tid; i < FIN * 64; i += 256) {
        int j = i & 7, l = (i >> 3) & 63, t = i >> 9;
        int kc = t >> 2, nt = t & 3;
        int k = kc * 32 + (l >> 4) * 8 + j;
        int n = nt * 16 + (l & 15);
        s_B[i] = (_Float16)wa[k * 64 + n];
    }

    float scv[2][8], shv[2][8];
    if (APPLY) {
        #pragma unroll
        for (int kc = 0; kc < 2; kc++)
            #pragma unroll
            for (int j = 0; j < 8; j++) {
                int c = kc * 32 + q * 8 + j;
                float s0 = 0.f, s1 = 0.f;
                #pragma unroll
                for (int r = 0; r < NREP; r++) {
                    s0 += stats_in[r * 128 + c];
                    s1 += stats_in[r * 128 + 64 + c];
                }
                float mean = s0 * (1.0f / NN);
                float var  = s1 * (1.0f / NN) - mean * mean;
                float rstd = rsqrtf(var + BN_EPS);
                float s    = rstd * g_in[c];
                scv[kc][j] = s;
                shv[kc][j] = be_in[c] - mean * s;
            }
    }
    __syncthreads();

    int g = blockIdx.x * 4 + w;
    if (g >= NGROUP) return;
    const int row = g * 16 + mm;

    half8 af[KC];
    if (FIN == 128) {
        const float* xin = (const float*)in_v;
        #pragma unroll
        for (int kc = 0; kc < KC; kc++) {
            const float* p = xin + (size_t)row * 128 + kc * 32 + q * 8;
            float4 a = *(const float4*)p;
            float4 b = *(const float4*)(p + 4);
            half8 hv;
            hv[0] = (_Float16)a.x; hv[1] = (_Float16)a.y;
            hv[2] = (_Float16)a.z; hv[3] = (_Float16)a.w;
            hv[4] = (_Float16)b.x; hv[5] = (_Float16)b.y;
            hv[6] = (_Float16)b.z; hv[7] = (_Float16)b.w;
            af[kc] = hv;
        }
    } else {
        const ushort* hin = (const ushort*)in_v;
        #pragma unroll
        for (int kc = 0; kc < KC; kc++) {
            uint4 vv = *(const uint4*)(hin + (size_t)row * 64 + kc * 32 + q * 8);
            float f[8]; unpack8(vv, f);
            half8 hv;
            #pragma unroll
            for (int j = 0; j < 8; j++) {
                float z = APPLY ? fmaxf(fmaf(f[j], scv[kc][j], shv[kc][j]), 0.0f) : f[j];
                hv[j] = (_Float16)z;
            }
            af[kc] = hv;
        }
    }

    floatx4 acc[4] = {};
    #pragma unroll
    for (int nt = 0; nt < 4; nt++)
        #pragma unroll
        for (int kc = 0; kc < KC; kc++) {
            half8 bf = *(const half8*)(s_B + ((size_t)(kc * 4 + nt) * 64 + lane) * 8);
            acc[nt] = __builtin_amdgcn_mfma_f32_16x16x32_f16(af[kc], bf, acc[nt], 0, 0, 0);
        }

    _Float16* s_Yw = &s_Y[w][0];
    #pragma unroll
    for (int nt = 0; nt < 4; nt++)
        #pragma unroll
        for (int r = 0; r < 4; r++)
            s_Yw[(q * 4 + r) * 64 + nt * 16 + mm] = (_Float16)acc[nt][r];
    half8 t0 = *(const half8*)(s_Yw + lane * 8);
    half8 t1 = *(const half8*)(s_Yw + 512 + lane * 8);
    half8* dst = (half8*)((_Float16*)y_out + (size_t)g * 1024);
    dst[lane] = t0;
    dst[64 + lane] = t1;
}

// ======== gather: 512 thr = 8 waves = 2 groups/block; wave = ONE 4-row batch ========
// 1563 blocks (~6 blocks/CU demand, up to 32 waves/CU resident) for latency hiding.
// Inner loop is round-1's register-lean form: 1-deep prefetch + packed fp16 accum
// (fits the 64-VGPR cap of launch_bounds(512,4) with NO spill -- rounds 2/3/5's poison).
__global__ __launch_bounds__(512, 4) void gin_gather_kernel(
    const ushort* __restrict__ y,
    const int* __restrict__ rowPtr, const int* __restrict__ csr_src,
    const float* __restrict__ eps_p, const float* __restrict__ ba,
    const _Float16* __restrict__ wbh, const float* __restrict__ bb,
    ushort* __restrict__ h_out, float* __restrict__ stats_out)
{
    __shared__ __align__(16) _Float16 s_B2[64 * 64];
    __shared__ __align__(16) _Float16 s_A[2][1024];
    __shared__ float s_red[2][128];

    const int tid = threadIdx.x, w = tid >> 6, lane = tid & 63;
    const int gl = w >> 2;          // group-local index (0/1)
    const int m  = (w & 3) * 4;     // this wave's 4-row batch within the group
    const int cc = lane & 7, gph = lane >> 3;
    const int q = lane >> 4, mm = lane & 15;

    // coalesced B2 stage: 512 x 16B from pre-packed wbh
    ((half8*)s_B2)[tid] = ((const half8*)wbh)[tid];
    if (tid < 256) ((float*)s_red)[tid] = 0.0f;

    const float eps1 = 1.0f + eps_p[0];
    __syncthreads();

    const uint4* y4 = (const uint4*)y;
    const int g = blockIdx.x * 2 + gl;

    if (g < NGROUP) {
        const int row0 = g * 16;
        _Float16* s_Aw = &s_A[gl][0];

        int e[4], en[4], s[4];
        uint4 v[4];
        uint4 pk[4];
        #pragma unroll
        for (int i = 0; i < 4; i++) {
            int row = row0 + m + i;
            e[i] = rowPtr[row] + gph;
            en[i] = rowPtr[row + 1];
            pk[i].x = pk[i].y = pk[i].z = pk[i].w = 0u;
        }
        #pragma unroll
        for (int i = 0; i < 4; i++) s[i] = (e[i] < en[i]) ? csr_src[e[i]] : -1;
        #pragma unroll
        for (int i = 0; i < 4; i++) if (s[i] >= 0) v[i] = y4[(size_t)s[i] * 8 + cc];

        int mx = max(max(s[0], s[1]), max(s[2], s[3]));
        while (mx >= 0) {
            int n[4]; uint4 p[4];
            #pragma unroll
            for (int i = 0; i < 4; i++) {
                n[i] = -1;
                if (s[i] >= 0) { e[i] += 8; n[i] = (e[i] < en[i]) ? csr_src[e[i]] : -1; }
            }
            #pragma unroll
            for (int i = 0; i < 4; i++) if (n[i] >= 0) p[i] = y4[(size_t)n[i] * 8 + cc];
            #pragma unroll
            for (int i = 0; i < 4; i++) {
                if (s[i] >= 0) pkadd4(pk[i], v[i]);
                s[i] = n[i]; v[i] = p[i];
            }
            mx = max(max(s[0], s[1]), max(s[2], s[3]));
        }

        // Flush + reduce + store ONE ROW AT A TIME (8 live floats).
        #pragma unroll
        for (int i = 0; i < 4; i++) {
            float a[8];
            unpack8(pk[i], a);
            if (gph == 0) {
                uint4 sv = y4[(size_t)(row0 + m + i) * 8 + cc];
                float f[8]; unpack8(sv, f);
                #pragma unroll
                for (int j = 0; j < 8; j++) a[j] = fmaf(eps1, f[j], a[j]);
            }
            #pragma unroll
            for (int off = 8; off < 64; off <<= 1)
                #pragma unroll
                for (int j = 0; j < 8; j++)
                    a[j] += __shfl_xor(a[j], off, 64);
            if (gph == 0) {
                half8 hv;
                #pragma unroll
                for (int j = 0; j < 8; j++)
                    hv[j] = (_Float16)fmaxf(a[j] + ba[8 * cc + j], 0.0f);
                int slot = (cc >> 2) * 64 + (cc & 3) * 16 + (m + i);
                *(half8*)(s_Aw + (size_t)aswz(slot) * 8) = hv;
            }
        }
    }
    __syncthreads();

    // ---- GEMM2 + epilogue + BN partial stats: one wave per group ----
    if ((w & 3) == 0 && g < NGROUP) {
        const int row0 = g * 16;
        _Float16* s_Aw = &s_A[gl][0];
        float bbv[4];
        #pragma unroll
        for (int nt = 0; nt < 4; nt++) bbv[nt] = bb[nt * 16 + mm];

        half8 af2[2];
        #pragma unroll
        for (int kc = 0; kc < 2; kc++)
            af2[kc] = *(const half8*)(s_Aw + (size_t)aswz(kc * 64 + lane) * 8);
        floatx4 acc2[4] = {};
        #pragma unroll
        for (int nt = 0; nt < 4; nt++)
            #pragma unroll
            for (int kc = 0; kc < 2; kc++) {
                half8 bf = *(const half8*)(s_B2 + ((size_t)(kc * 4 + nt) * 64 + lane) * 8);
                acc2[nt] = __builtin_amdgcn_mfma_f32_16x16x32_f16(af2[kc], bf, acc2[nt], 0, 0, 0);
            }

        float bn_s[4] = {0.f, 0.f, 0.f, 0.f};
        float bn_q[4] = {0.f, 0.f, 0.f, 0.f};
        #pragma unroll
        for (int nt = 0; nt < 4; nt++)
            #pragma unroll
            for (int r = 0; r < 4; r++) {
                float val = fmaxf(acc2[nt][r] + bbv[nt], 0.0f);
                bn_s[nt] += val;
                bn_q[nt] += val * val;
                s_Aw[(q * 4 + r) * 64 + nt * 16 + mm] = (_Float16)val;
            }
        half8 t0 = *(const half8*)(s_Aw + lane * 8);
        half8 t1 = *(const half8*)(s_Aw + 512 + lane * 8);
        half8* dst = (half8*)((_Float16*)h_out + (size_t)row0 * 64);
        dst[lane] = t0;
        dst[64 + lane] = t1;

        #pragma unroll
        for (int nt = 0; nt < 4; nt++) {
            bn_s[nt] += __shfl_xor(bn_s[nt], 16, 64);
            bn_s[nt] += __shfl_xor(bn_s[nt], 32, 64);
            bn_q[nt] += __shfl_xor(bn_q[nt], 16, 64);
            bn_q[nt] += __shfl_xor(bn_q[nt], 32, 64);
        }
        if (lane < 16) {
            #pragma unroll
            for (int nt = 0; nt < 4; nt++) {
                s_red[gl][nt * 16 + lane]      = bn_s[nt];
                s_red[gl][64 + nt * 16 + lane] = bn_q[nt];
            }
        }
    }
    __syncthreads();
    if (w == 0) {
        float* srep = stats_out + (size_t)(blockIdx.x & (NREP - 1)) * 128;
        atomicAdd(&srep[lane],      s_red[0][lane]      + s_red[1][lane]);
        atomicAdd(&srep[64 + lane], s_red[0][64 + lane] + s_red[1][64 + lane]);
    }
}

// ---------------- final: BN+ReLU of layer 3 (fp16 h), then (N,64)@(64,10)+b ----------------
__global__ __launch_bounds__(256) void final_linear_kernel(
    const ushort* __restrict__ h, const float* __restrict__ stats,
    const float* __restrict__ g, const float* __restrict__ be,
    const float* __restrict__ w, const float* __restrict__ b,
    float* __restrict__ out)
{
    __shared__ float s_w[640];
    __shared__ float s_b[10];
    __shared__ float s_scale[64];
    __shared__ float s_shift[64];
    for (int i = threadIdx.x; i < 640; i += 256) s_w[i] = w[i];
    if (threadIdx.x < 10) s_b[threadIdx.x] = b[threadIdx.x];
    if (threadIdx.x < 64) {
        int c = threadIdx.x;
        float s0 = 0.f, s1 = 0.f;
        #pragma unroll
        for (int r = 0; r < NREP; r++) {
            s0 += stats[r * 128 + c];
            s1 += stats[r * 128 + 64 + c];
        }
        float mean = s0 * (1.0f / NN);
        float var  = s1 * (1.0f / NN) - mean * mean;
        float rstd = rsqrtf(var + BN_EPS);
        float s    = rstd * g[c];
        s_scale[c] = s;
        s_shift[c] = be[c] - mean * s;
    }
    __syncthreads();
    int row = blockIdx.x * 256 + threadIdx.x;
    if (row >= NN) return;
    float acc[10];
    #pragma unroll
    for (int c = 0; c < 10; c++) acc[c] = s_b[c];
    const uint4* hr = (const uint4*)(h + (size_t)row * 64);
    #pragma unroll
    for (int ch = 0; ch < 8; ch++) {
        uint4 v = hr[ch];
        float f[8]; unpack8(v, f);
        #pragma unroll
        for (int j = 0; j < 8; j++) {
            int k = ch * 8 + j;
            float val = fmaxf(fmaf(f[j], s_scale[k], s_shift[k]), 0.0f);
            #pragma unroll
            for (int c = 0; c < 10; c++) acc[c] = fmaf(val, s_w[k * 10 + c], acc[c]);
        }
    }
    #pragma unroll
    for (int c = 0; c < 10; c++) out[row * 10 + c] = acc[c];
}

extern "C" void kernel_launch(void* const* d_in, const int* in_sizes, int n_in,
                              void* d_out, int out_size, void* d_ws, size_t ws_size,
                              hipStream_t stream)
{
    const float* x  = (const float*)d_in[0];
    const int*   ei = (const int*)d_in[1];
    const int E = in_sizes[1] / 2;

    const float* eps[3]; const float* wa[3]; const float* ba[3];
    const float* wb[3];  const float* bb[3]; const float* g[3]; const float* be[3];
    for (int i = 0; i < 3; i++) {
        int base = 2 + 7 * i;
        eps[i] = (const float*)d_in[base + 0];
        wa[i]  = (const float*)d_in[base + 1];
        ba[i]  = (const float*)d_in[base + 2];
        wb[i]  = (const float*)d_in[base + 3];
        bb[i]  = (const float*)d_in[base + 4];
        g[i]   = (const float*)d_in[base + 5];
        be[i]  = (const float*)d_in[base + 6];
    }
    const float* lin_w = (const float*)d_in[23];
    const float* lin_b = (const float*)d_in[24];
    float* out = (float*)d_out;

    // workspace layout: gcur and stats adjacent -> single zeroing memset
    char*  base   = (char*)d_ws;
    int*   gcur   = (int*)base;               // 512 ints
    float* stats  = (float*)(gcur + 512);     // 3 layers x NREP x 128 floats
    int*   rowPtr = (int*)(stats + 3 * NREP * 128);  // NN+1
    uint*  bucket = (uint*)(rowPtr + NN + 1); // NCHUNK*CHCAP
    int*   csrsrc = (int*)(bucket + (size_t)NCHUNK * CHCAP);  // E
    size_t hoff   = (char*)(csrsrc + E) - base;
    _Float16* wbh = (_Float16*)(base + ((hoff + 15) & ~(size_t)15));  // 4096
    ushort* yb    = (ushort*)(wbh + 4096);    // NN*64
    ushort* hA    = yb + (size_t)NN * 64;     // NN*64
    ushort* hB    = hA + (size_t)NN * 64;     // NN*64

    // ---- CSR build (bucketed) ----
    hipMemsetAsync(gcur, 0, (512 + 3 * NREP * 128) * sizeof(int), stream);
    sortA_kernel<<<(E + SLAB - 1) / SLAB, 256, 0, stream>>>(ei, gcur, bucket, E);
    fillB_kernel<<<NCHUNK, 256, 0, stream>>>(bucket, gcur, rowPtr, csrsrc);

    const int PB = (NGROUP + 3) / 4;   // 782 proj blocks
    const int GB = (NGROUP + 1) / 2;   // 1563 gather blocks (2 groups/block, wave=4-row batch)

    // ---- layer 1: proj x (fp32,128) -> y; fused gather+MLP ----
    proj_kernel<128, false><<<PB, 256, 0, stream>>>(
        x, nullptr, nullptr, nullptr, wa[0], wb[0], wbh, yb);
    gin_gather_kernel<<<GB, 512, 0, stream>>>(
        yb, rowPtr, csrsrc, eps[0], ba[0], wbh, bb[0], hA, stats);
    // ---- layer 2 ----
    proj_kernel<64, true><<<PB, 256, 0, stream>>>(
        hA, stats, g[0], be[0], wa[1], wb[1], wbh, yb);
    gin_gather_kernel<<<GB, 512, 0, stream>>>(
        yb, rowPtr, csrsrc, eps[1], ba[1], wbh, bb[1], hB, stats + NREP * 128);
    // ---- layer 3 ----
    proj_kernel<64, true><<<PB, 256, 0, stream>>>(
        hB, stats + NREP * 128, g[1], be[1], wa[2], wb[2], wbh, yb);
    gin_gather_kernel<<<GB, 512, 0, stream>>>(
        yb, rowPtr, csrsrc, eps[2], ba[2], wbh, bb[2], hA, stats + 2 * NREP * 128);
    // ---- final ----
    final_linear_kernel<<<(NN + 255) / 256, 256, 0, stream>>>(
        hA, stats + 2 * NREP * 128, g[2], be[2], lin_w, lin_b, out);
}

// Round 7
// 314.504 us; speedup vs baseline: 1.1175x; 1.0257x over previous
//
#include <hip/hip_runtime.h>
#include <hip/hip_fp16.h>

#define NN 50000
#define NGROUP 3125   // NN / 16 (exact)
#define NCHUNK 391    // ceil(NN / 128)
#define CHCAP 3072    // bucket capacity per chunk (expected ~2046)
#define SLAB 2048     // 391 sortA blocks (R0's 8192 -> 98 blocks = 0.4/CU, GPU mostly idle)
#define NREP 8        // stats atomic replication factor
#define BN_EPS 1e-5f

typedef unsigned int uint;
typedef unsigned short ushort;
typedef _Float16 half8 __attribute__((ext_vector_type(8)));
typedef _Float16 half2t __attribute__((ext_vector_type(2)));
typedef float floatx4 __attribute__((ext_vector_type(4)));

__device__ __forceinline__ int aswz(int slot) { return slot ^ ((slot >> 4) & 7); }

__device__ __forceinline__ float h_lo(uint u) {
    return __half2float(__ushort_as_half((ushort)(u & 0xFFFFu)));
}
__device__ __forceinline__ float h_hi(uint u) {
    return __half2float(__ushort_as_half((ushort)(u >> 16)));
}
__device__ __forceinline__ void unpack8(uint4 v, float* f) {
    f[0] = h_lo(v.x); f[1] = h_hi(v.x);
    f[2] = h_lo(v.y); f[3] = h_hi(v.y);
    f[4] = h_lo(v.z); f[5] = h_hi(v.z);
    f[6] = h_lo(v.w); f[7] = h_hi(v.w);
}
// packed fp16 add: 2 channels per op (v_pk_add_f16)
__device__ __forceinline__ uint pkadd(uint a, uint b) {
    half2t x = __builtin_bit_cast(half2t, a);
    half2t y = __builtin_bit_cast(half2t, b);
    half2t r = x + y;
    return __builtin_bit_cast(uint, r);
}
__device__ __forceinline__ void pkadd4(uint4& a, uint4 b) {
    a.x = pkadd(a.x, b.x); a.y = pkadd(a.y, b.y);
    a.z = pkadd(a.z, b.z); a.w = pkadd(a.w, b.w);
}

// ================= CSR phase A: 391 blocks, two-pass (no per-thread scratch) =================
__global__ __launch_bounds__(256) void sortA_kernel(
    const int* __restrict__ ei, int* __restrict__ gcur,
    uint* __restrict__ bucket, int E)
{
    __shared__ int s_hist[NCHUNK];
    __shared__ int s_offs[NCHUNK];
    __shared__ int s_cur[NCHUNK];
    __shared__ int s_gb[NCHUNK];
    __shared__ int s_scanA[512], s_scanB[512];
    __shared__ uint s_sorted[SLAB];

    const int tid  = threadIdx.x;
    const int base = blockIdx.x * SLAB;
    const int cnt  = min(SLAB, E - base);

    for (int i = tid; i < NCHUNK; i += 256) s_hist[i] = 0;
    __syncthreads();
    for (int i = tid; i < cnt; i += 256) {
        int dst = ei[E + base + i];
        atomicAdd(&s_hist[dst >> 7], 1);
    }
    __syncthreads();
    for (int i = tid; i < 512; i += 256) s_scanA[i] = (i < NCHUNK) ? s_hist[i] : 0;
    __syncthreads();
    int* sa = s_scanA; int* sb = s_scanB;
    for (int off = 1; off < 512; off <<= 1) {
        for (int i = tid; i < 512; i += 256)
            sb[i] = sa[i] + ((i >= off) ? sa[i - off] : 0);
        __syncthreads();
        int* t = sa; sa = sb; sb = t;
    }
    for (int i = tid; i < NCHUNK; i += 256) {
        int excl = sa[i] - s_hist[i];
        s_offs[i] = excl;
        s_cur[i]  = excl;
    }
    __syncthreads();
    for (int i = tid; i < cnt; i += 256) {
        int src = ei[base + i];          // second pass: L2-warm
        int dst = ei[E + base + i];
        int c = dst >> 7;
        uint v = (uint)src | ((uint)(dst & 127) << 16) | ((uint)c << 23);
        int pos = atomicAdd(&s_cur[c], 1);
        s_sorted[pos] = v;
    }
    __syncthreads();
    for (int c = tid; c < NCHUNK; c += 256) {
        int n = s_hist[c];
        s_gb[c] = n ? atomicAdd(&gcur[c], n) : 0;
    }
    __syncthreads();
    for (int i = tid; i < cnt; i += 256) {
        uint v = s_sorted[i];
        int c = v >> 23;
        int li = i - s_offs[c];
        bucket[(size_t)c * CHCAP + s_gb[c] + li] = v;
    }
}

// phase B: one block per chunk — inline base scan + per-row hist/scan -> rowPtr + dense fill.
__global__ __launch_bounds__(256) void fillB_kernel(
    const uint* __restrict__ bucket, const int* __restrict__ gcur,
    int* __restrict__ rowPtr, int* __restrict__ csr_src)
{
    __shared__ int s_hist[128];
    __shared__ int s_excl[128];
    __shared__ int s_cur[128];
    __shared__ int s_ws[4];
    __shared__ int s_base;
    const int c = blockIdx.x;
    const int tid = threadIdx.x;
    const int cnt = gcur[c];
    const int row0 = c * 128;

    int part = 0;
    for (int i = tid; i < c; i += 256) part += gcur[i];
    #pragma unroll
    for (int off = 32; off >= 1; off >>= 1) part += __shfl_down(part, off, 64);
    if ((tid & 63) == 0) s_ws[tid >> 6] = part;
    if (tid < 128) s_hist[tid] = 0;
    __syncthreads();
    if (tid == 0) s_base = s_ws[0] + s_ws[1] + s_ws[2] + s_ws[3];
    __syncthreads();
    const int base = s_base;
    if (tid == 0 && c == NCHUNK - 1) rowPtr[NN] = base + cnt;

    for (int i = tid; i < cnt; i += 256) {
        uint v = bucket[(size_t)c * CHCAP + i];
        atomicAdd(&s_hist[(v >> 16) & 127], 1);
    }
    __syncthreads();
    if (tid < 128) {
        int lane = tid & 63;
        int v = s_hist[tid];
        int incl = v;
        #pragma unroll
        for (int off = 1; off < 64; off <<= 1) {
            int t = __shfl_up(incl, off, 64);
            if (lane >= off) incl += t;
        }
        s_excl[tid] = incl - v;
    }
    __syncthreads();
    if (tid < 128) {
        int excl = s_excl[tid];
        if (tid >= 64) excl += s_excl[63] + s_hist[63];
        s_cur[tid] = excl;
        int row = row0 + tid;
        if (row < NN) rowPtr[row] = base + excl;
    }
    __syncthreads();
    for (int i = tid; i < cnt; i += 256) {
        uint v = bucket[(size_t)c * CHCAP + i];
        int dl  = (v >> 16) & 127;
        int src = v & 0xFFFFu;
        int ofs = atomicAdd(&s_cur[dl], 1);
        csr_src[base + ofs] = src;
    }
}

// ======== proj: y = W_a^T * z, z = BNReLU(h_in) [APPLY] or cvt(x) [layer 1] ========
// Side job: blocks 0..7 pre-pack this layer's wb into fp16 gather layout (wbh).
template<int FIN, bool APPLY>
__global__ __launch_bounds__(256, 4) void proj_kernel(
    const void* __restrict__ in_v,
    const float* __restrict__ stats_in, const float* __restrict__ g_in,
    const float* __restrict__ be_in,
    const float* __restrict__ wa,
    const float* __restrict__ wb_src, _Float16* __restrict__ wbh_out,
    ushort* __restrict__ y_out)
{
    constexpr int KC = FIN / 32;
    __shared__ __align__(16) _Float16 s_B[FIN * 64];
    __shared__ __align__(16) _Float16 s_Y[4][1024];

    const int tid = threadIdx.x, w = tid >> 6, lane = tid & 63;
    const int q = lane >> 4, mm = lane & 15;

    if (blockIdx.x < 8) {
        for (int t = tid; t < 512; t += 256) {
            int i = blockIdx.x * 512 + t;
            int j = i & 7, l = (i >> 3) & 63, tt = i >> 9;
            int kc = tt >> 2, nt = tt & 3;
            int k = kc * 32 + (l >> 4) * 8 + j;
            int n = nt * 16 + (l & 15);
            wbh_out[i] = (_Float16)wb_src[k * 64 + n];
        }
    }

    for (int i = tid; i < FIN * 64; i += 256) {
        int j = i & 7, l = (i >> 3) & 63, t = i >> 9;
        int kc = t >> 2, nt = t & 3;
        int k = kc * 32 + (l >> 4) * 8 + j;
        int n = nt * 16 + (l & 15);
        s_B[i] = (_Float16)wa[k * 64 + n];
    }

    float scv[2][8], shv[2][8];
    if (APPLY) {
        #pragma unroll
        for (int kc = 0; kc < 2; kc++)
            #pragma unroll
            for (int j = 0; j < 8; j++) {
                int c = kc * 32 + q * 8 + j;
                float s0 = 0.f, s1 = 0.f;
                #pragma unroll
                for (int r = 0; r < NREP; r++) {
                    s0 += stats_in[r * 128 + c];
                    s1 += stats_in[r * 128 + 64 + c];
                }
                float mean = s0 * (1.0f / NN);
                float var  = s1 * (1.0f / NN) - mean * mean;
                float rstd = rsqrtf(var + BN_EPS);
                float s    = rstd * g_in[c];
                scv[kc][j] = s;
                shv[kc][j] = be_in[c] - mean * s;
            }
    }
    __syncthreads();

    int g = blockIdx.x * 4 + w;
    if (g >= NGROUP) return;
    const int row = g * 16 + mm;

    half8 af[KC];
    if (FIN == 128) {
        const float* xin = (const float*)in_v;
        #pragma unroll
        for (int kc = 0; kc < KC; kc++) {
            const float* p = xin + (size_t)row * 128 + kc * 32 + q * 8;
            float4 a = *(const float4*)p;
            float4 b = *(const float4*)(p + 4);
            half8 hv;
            hv[0] = (_Float16)a.x; hv[1] = (_Float16)a.y;
            hv[2] = (_Float16)a.z; hv[3] = (_Float16)a.w;
            hv[4] = (_Float16)b.x; hv[5] = (_Float16)b.y;
            hv[6] = (_Float16)b.z; hv[7] = (_Float16)b.w;
            af[kc] = hv;
        }
    } else {
        const ushort* hin = (const ushort*)in_v;
        #pragma unroll
        for (int kc = 0; kc < KC; kc++) {
            uint4 vv = *(const uint4*)(hin + (size_t)row * 64 + kc * 32 + q * 8);
            float f[8]; unpack8(vv, f);
            half8 hv;
            #pragma unroll
            for (int j = 0; j < 8; j++) {
                float z = APPLY ? fmaxf(fmaf(f[j], scv[kc][j], shv[kc][j]), 0.0f) : f[j];
                hv[j] = (_Float16)z;
            }
            af[kc] = hv;
        }
    }

    floatx4 acc[4] = {};
    #pragma unroll
    for (int nt = 0; nt < 4; nt++)
        #pragma unroll
        for (int kc = 0; kc < KC; kc++) {
            half8 bf = *(const half8*)(s_B + ((size_t)(kc * 4 + nt) * 64 + lane) * 8);
            acc[nt] = __builtin_amdgcn_mfma_f32_16x16x32_f16(af[kc], bf, acc[nt], 0, 0, 0);
        }

    _Float16* s_Yw = &s_Y[w][0];
    #pragma unroll
    for (int nt = 0; nt < 4; nt++)
        #pragma unroll
        for (int r = 0; r < 4; r++)
            s_Yw[(q * 4 + r) * 64 + nt * 16 + mm] = (_Float16)acc[nt][r];
    half8 t0 = *(const half8*)(s_Yw + lane * 8);
    half8 t1 = *(const half8*)(s_Yw + 512 + lane * 8);
    half8* dst = (half8*)((_Float16*)y_out + (size_t)g * 1024);
    dst[lane] = t0;
    dst[64 + lane] = t1;
}

// ======== gather (round-0 proven decomposition): 391 blocks, 512 thr, 1 wave owns
// one 16-row group (4 serial 4-row batches, 1-deep value prefetch). Changes vs R0:
// packed-fp16 accumulation (live set -16 regs, fits the 64-VGPR allocation), inline
// ba at flush, coalesced s_B2 stage from pre-packed wbh, NREP stats replicas. ========
__global__ __launch_bounds__(512, 4) void gin_gather_kernel(
    const ushort* __restrict__ y,
    const int* __restrict__ rowPtr, const int* __restrict__ csr_src,
    const float* __restrict__ eps_p, const _Float16* __restrict__ wbh,
    const float* __restrict__ ba, const float* __restrict__ bb,
    ushort* __restrict__ h_out, float* __restrict__ stats_out)
{
    __shared__ __align__(16) _Float16 s_B2[64 * 64];
    __shared__ __align__(16) _Float16 s_A[8][1024];
    __shared__ float s_red[8][64];

    const int tid = threadIdx.x, w = tid >> 6, lane = tid & 63;
    const int cc = lane & 7, gph = lane >> 3;
    const int q = lane >> 4, mm = lane & 15;

    // coalesced B2 stage: 512 x 16B from pre-packed wbh
    ((half8*)s_B2)[tid] = ((const half8*)wbh)[tid];

    const float eps1 = 1.0f + eps_p[0];
    __syncthreads();

    float bn_s[4] = {0.f, 0.f, 0.f, 0.f};
    float bn_q[4] = {0.f, 0.f, 0.f, 0.f};
    const uint4* y4 = (const uint4*)y;
    const int g = blockIdx.x * 8 + w;

    if (g < NGROUP) {
        const int row0 = g * 16;
        _Float16* s_Aw = &s_A[w][0];

        for (int m = 0; m < 16; m += 4) {
            int e[4], en[4], s[4];
            uint4 v[4];
            uint4 pk[4];
            #pragma unroll
            for (int i = 0; i < 4; i++) {
                int row = row0 + m + i;
                e[i] = rowPtr[row] + gph;
                en[i] = rowPtr[row + 1];
                pk[i].x = pk[i].y = pk[i].z = pk[i].w = 0u;
            }
            #pragma unroll
            for (int i = 0; i < 4; i++) s[i] = (e[i] < en[i]) ? csr_src[e[i]] : -1;
            #pragma unroll
            for (int i = 0; i < 4; i++) if (s[i] >= 0) v[i] = y4[(size_t)s[i] * 8 + cc];

            int mx = max(max(s[0], s[1]), max(s[2], s[3]));
            while (mx >= 0) {
                int n[4]; uint4 p[4];
                #pragma unroll
                for (int i = 0; i < 4; i++) {
                    n[i] = -1;
                    if (s[i] >= 0) { e[i] += 8; n[i] = (e[i] < en[i]) ? csr_src[e[i]] : -1; }
                }
                #pragma unroll
                for (int i = 0; i < 4; i++) if (n[i] >= 0) p[i] = y4[(size_t)n[i] * 8 + cc];
                #pragma unroll
                for (int i = 0; i < 4; i++) {
                    if (s[i] >= 0) pkadd4(pk[i], v[i]);
                    s[i] = n[i]; v[i] = p[i];
                }
                mx = max(max(s[0], s[1]), max(s[2], s[3]));
            }

            // Flush + reduce + store ONE ROW AT A TIME (8 live floats).
            #pragma unroll
            for (int i = 0; i < 4; i++) {
                float a[8];
                unpack8(pk[i], a);
                if (gph == 0) {
                    uint4 sv = y4[(size_t)(row0 + m + i) * 8 + cc];
                    float f[8]; unpack8(sv, f);
                    #pragma unroll
                    for (int j = 0; j < 8; j++) a[j] = fmaf(eps1, f[j], a[j]);
                }
                #pragma unroll
                for (int off = 8; off < 64; off <<= 1)
                    #pragma unroll
                    for (int j = 0; j < 8; j++)
                        a[j] += __shfl_xor(a[j], off, 64);
                if (gph == 0) {
                    half8 hv;
                    #pragma unroll
                    for (int j = 0; j < 8; j++)
                        hv[j] = (_Float16)fmaxf(a[j] + ba[8 * cc + j], 0.0f);
                    int slot = (cc >> 2) * 64 + (cc & 3) * 16 + (m + i);
                    *(half8*)(s_Aw + (size_t)aswz(slot) * 8) = hv;
                }
            }
        }

        float bbv[4];
        #pragma unroll
        for (int nt = 0; nt < 4; nt++) bbv[nt] = bb[nt * 16 + mm];

        half8 af2[2];
        #pragma unroll
        for (int kc = 0; kc < 2; kc++)
            af2[kc] = *(const half8*)(s_Aw + (size_t)aswz(kc * 64 + lane) * 8);
        floatx4 acc2[4] = {};
        #pragma unroll
        for (int nt = 0; nt < 4; nt++)
            #pragma unroll
            for (int kc = 0; kc < 2; kc++) {
                half8 bf = *(const half8*)(s_B2 + ((size_t)(kc * 4 + nt) * 64 + lane) * 8);
                acc2[nt] = __builtin_amdgcn_mfma_f32_16x16x32_f16(af2[kc], bf, acc2[nt], 0, 0, 0);
            }

        #pragma unroll
        for (int nt = 0; nt < 4; nt++)
            #pragma unroll
            for (int r = 0; r < 4; r++) {
                float val = fmaxf(acc2[nt][r] + bbv[nt], 0.0f);
                bn_s[nt] += val;
                bn_q[nt] += val * val;
                s_Aw[(q * 4 + r) * 64 + nt * 16 + mm] = (_Float16)val;
            }
        half8 t0 = *(const half8*)(s_Aw + lane * 8);
        half8 t1 = *(const half8*)(s_Aw + 512 + lane * 8);
        half8* dst = (half8*)((_Float16*)h_out + (size_t)row0 * 64);
        dst[lane] = t0;
        dst[64 + lane] = t1;
    }

    #pragma unroll
    for (int nt = 0; nt < 4; nt++) {
        bn_s[nt] += __shfl_xor(bn_s[nt], 16, 64);
        bn_s[nt] += __shfl_xor(bn_s[nt], 32, 64);
        bn_q[nt] += __shfl_xor(bn_q[nt], 16, 64);
        bn_q[nt] += __shfl_xor(bn_q[nt], 32, 64);
    }
    __syncthreads();
    if (lane < 16) {
        #pragma unroll
        for (int nt = 0; nt < 4; nt++) s_red[w][nt * 16 + lane] = bn_s[nt];
    }
    __syncthreads();
    if (w == 0) {
        float s = 0;
        #pragma unroll
        for (int j = 0; j < 8; j++) s += s_red[j][lane];
        atomicAdd(&stats_out[(size_t)(blockIdx.x & (NREP - 1)) * 128 + lane], s);
    }
    __syncthreads();
    if (lane < 16) {
        #pragma unroll
        for (int nt = 0; nt < 4; nt++) s_red[w][nt * 16 + lane] = bn_q[nt];
    }
    __syncthreads();
    if (w == 0) {
        float s = 0;
        #pragma unroll
        for (int j = 0; j < 8; j++) s += s_red[j][lane];
        atomicAdd(&stats_out[(size_t)(blockIdx.x & (NREP - 1)) * 128 + 64 + lane], s);
    }
}

// ---------------- final: BN+ReLU of layer 3 (fp16 h), then (N,64)@(64,10)+b ----------------
__global__ __launch_bounds__(256) void final_linear_kernel(
    const ushort* __restrict__ h, const float* __restrict__ stats,
    const float* __restrict__ g, const float* __restrict__ be,
    const float* __restrict__ w, const float* __restrict__ b,
    float* __restrict__ out)
{
    __shared__ float s_w[640];
    __shared__ float s_b[10];
    __shared__ float s_scale[64];
    __shared__ float s_shift[64];
    for (int i = threadIdx.x; i < 640; i += 256) s_w[i] = w[i];
    if (threadIdx.x < 10) s_b[threadIdx.x] = b[threadIdx.x];
    if (threadIdx.x < 64) {
        int c = threadIdx.x;
        float s0 = 0.f, s1 = 0.f;
        #pragma unroll
        for (int r = 0; r < NREP; r++) {
            s0 += stats[r * 128 + c];
            s1 += stats[r * 128 + 64 + c];
        }
        float mean = s0 * (1.0f / NN);
        float var  = s1 * (1.0f / NN) - mean * mean;
        float rstd = rsqrtf(var + BN_EPS);
        float s    = rstd * g[c];
        s_scale[c] = s;
        s_shift[c] = be[c] - mean * s;
    }
    __syncthreads();
    int row = blockIdx.x * 256 + threadIdx.x;
    if (row >= NN) return;
    float acc[10];
    #pragma unroll
    for (int c = 0; c < 10; c++) acc[c] = s_b[c];
    const uint4* hr = (const uint4*)(h + (size_t)row * 64);
    #pragma unroll
    for (int ch = 0; ch < 8; ch++) {
        uint4 v = hr[ch];
        float f[8]; unpack8(v, f);
        #pragma unroll
        for (int j = 0; j < 8; j++) {
            int k = ch * 8 + j;
            float val = fmaxf(fmaf(f[j], s_scale[k], s_shift[k]), 0.0f);
            #pragma unroll
            for (int c = 0; c < 10; c++) acc[c] = fmaf(val, s_w[k * 10 + c], acc[c]);
        }
    }
    #pragma unroll
    for (int c = 0; c < 10; c++) out[row * 10 + c] = acc[c];
}

extern "C" void kernel_launch(void* const* d_in, const int* in_sizes, int n_in,
                              void* d_out, int out_size, void* d_ws, size_t ws_size,
                              hipStream_t stream)
{
    const float* x  = (const float*)d_in[0];
    const int*   ei = (const int*)d_in[1];
    const int E = in_sizes[1] / 2;

    const float* eps[3]; const float* wa[3]; const float* ba[3];
    const float* wb[3];  const float* bb[3]; const float* g[3]; const float* be[3];
    for (int i = 0; i < 3; i++) {
        int base = 2 + 7 * i;
        eps[i] = (const float*)d_in[base + 0];
        wa[i]  = (const float*)d_in[base + 1];
        ba[i]  = (const float*)d_in[base + 2];
        wb[i]  = (const float*)d_in[base + 3];
        bb[i]  = (const float*)d_in[base + 4];
        g[i]   = (const float*)d_in[base + 5];
        be[i]  = (const float*)d_in[base + 6];
    }
    const float* lin_w = (const float*)d_in[23];
    const float* lin_b = (const float*)d_in[24];
    float* out = (float*)d_out;

    // workspace layout: gcur and stats adjacent -> single zeroing memset
    char*  base   = (char*)d_ws;
    int*   gcur   = (int*)base;               // 512 ints
    float* stats  = (float*)(gcur + 512);     // 3 layers x NREP x 128 floats
    int*   rowPtr = (int*)(stats + 3 * NREP * 128);  // NN+1
    uint*  bucket = (uint*)(rowPtr + NN + 1); // NCHUNK*CHCAP
    int*   csrsrc = (int*)(bucket + (size_t)NCHUNK * CHCAP);  // E
    size_t hoff   = (char*)(csrsrc + E) - base;
    _Float16* wbh = (_Float16*)(base + ((hoff + 15) & ~(size_t)15));  // 4096
    ushort* yb    = (ushort*)(wbh + 4096);    // NN*64
    ushort* hA    = yb + (size_t)NN * 64;     // NN*64
    ushort* hB    = hA + (size_t)NN * 64;     // NN*64

    // ---- CSR build (bucketed) ----
    hipMemsetAsync(gcur, 0, (512 + 3 * NREP * 128) * sizeof(int), stream);
    sortA_kernel<<<(E + SLAB - 1) / SLAB, 256, 0, stream>>>(ei, gcur, bucket, E);
    fillB_kernel<<<NCHUNK, 256, 0, stream>>>(bucket, gcur, rowPtr, csrsrc);

    const int PB = (NGROUP + 3) / 4;   // 782 proj blocks
    const int GB = (NGROUP + 7) / 8;   // 391 gather blocks (1 wave per group)

    // ---- layer 1: proj x (fp32,128) -> y; fused gather+MLP ----
    proj_kernel<128, false><<<PB, 256, 0, stream>>>(
        x, nullptr, nullptr, nullptr, wa[0], wb[0], wbh, yb);
    gin_gather_kernel<<<GB, 512, 0, stream>>>(
        yb, rowPtr, csrsrc, eps[0], wbh, ba[0], bb[0], hA, stats);
    // ---- layer 2 ----
    proj_kernel<64, true><<<PB, 256, 0, stream>>>(
        hA, stats, g[0], be[0], wa[1], wb[1], wbh, yb);
    gin_gather_kernel<<<GB, 512, 0, stream>>>(
        yb, rowPtr, csrsrc, eps[1], wbh, ba[1], bb[1], hB, stats + NREP * 128);
    // ---- layer 3 ----
    proj_kernel<64, true><<<PB, 256, 0, stream>>>(
        hB, stats + NREP * 128, g[1], be[1], wa[2], wb[2], wbh, yb);
    gin_gather_kernel<<<GB, 512, 0, stream>>>(
        yb, rowPtr, csrsrc, eps[2], wbh, ba[2], bb[2], hA, stats + 2 * NREP * 128);
    // ---- final ----
    final_linear_kernel<<<(NN + 255) / 256, 256, 0, stream>>>(
        hA, stats + 2 * NREP * 128, g[2], be[2], lin_w, lin_b, out);
}

// Round 10
// 308.923 us; speedup vs baseline: 1.1377x; 1.0181x over previous
//
#include <hip/hip_runtime.h>
#include <hip/hip_fp16.h>

#define NN 50000
#define NGROUP 3125   // NN / 16 (exact)
#define NCHUNK 391    // ceil(NN / 128)
#define CHCAP 3072    // bucket capacity per chunk (expected ~2046)
#define SLAB 8192     // R0-proven: 84B bucket segments; 2048 gave 21B scatter (R7 regression)
#define NREP 8        // stats atomic replication factor
#define BN_EPS 1e-5f

typedef unsigned int uint;
typedef unsigned short ushort;
typedef _Float16 half8 __attribute__((ext_vector_type(8)));
typedef _Float16 half2t __attribute__((ext_vector_type(2)));
typedef float floatx4 __attribute__((ext_vector_type(4)));

__device__ __forceinline__ int aswz(int slot) { return slot ^ ((slot >> 4) & 7); }

__device__ __forceinline__ float h_lo(uint u) {
    return __half2float(__ushort_as_half((ushort)(u & 0xFFFFu)));
}
__device__ __forceinline__ float h_hi(uint u) {
    return __half2float(__ushort_as_half((ushort)(u >> 16)));
}
__device__ __forceinline__ void unpack8(uint4 v, float* f) {
    f[0] = h_lo(v.x); f[1] = h_hi(v.x);
    f[2] = h_lo(v.y); f[3] = h_hi(v.y);
    f[4] = h_lo(v.z); f[5] = h_hi(v.z);
    f[6] = h_lo(v.w); f[7] = h_hi(v.w);
}
// packed fp16 add: 2 channels per op (v_pk_add_f16)
__device__ __forceinline__ uint pkadd(uint a, uint b) {
    half2t x = __builtin_bit_cast(half2t, a);
    half2t y = __builtin_bit_cast(half2t, b);
    half2t r = x + y;
    return __builtin_bit_cast(uint, r);
}
__device__ __forceinline__ void pkadd4(uint4& a, uint4 b) {
    a.x = pkadd(a.x, b.x); a.y = pkadd(a.y, b.y);
    a.z = pkadd(a.z, b.z); a.w = pkadd(a.w, b.w);
}

// ================= CSR build: R0-exact (SLAB 8192, one-pass, 98 blocks) =================
__global__ __launch_bounds__(256) void sortA_kernel(
    const int* __restrict__ ei, int* __restrict__ gcur,
    uint* __restrict__ bucket, int E)
{
    __shared__ int s_hist[NCHUNK];
    __shared__ int s_offs[NCHUNK];
    __shared__ int s_cur[NCHUNK];
    __shared__ int s_gb[NCHUNK];
    __shared__ int s_scanA[512], s_scanB[512];
    __shared__ uint s_sorted[SLAB];

    const int tid  = threadIdx.x;
    const int base = blockIdx.x * SLAB;
    const int cnt  = min(SLAB, E - base);

    for (int i = tid; i < NCHUNK; i += 256) s_hist[i] = 0;
    __syncthreads();

    uint pk[SLAB / 256];
    int nloc = 0;
    for (int i = tid; i < cnt; i += 256) {
        int src = ei[base + i];
        int dst = ei[E + base + i];
        int c = dst >> 7;
        pk[nloc++] = (uint)src | ((uint)(dst & 127) << 16) | ((uint)c << 23);
        atomicAdd(&s_hist[c], 1);
    }
    __syncthreads();
    for (int i = tid; i < 512; i += 256) s_scanA[i] = (i < NCHUNK) ? s_hist[i] : 0;
    __syncthreads();
    int* sa = s_scanA; int* sb = s_scanB;
    for (int off = 1; off < 512; off <<= 1) {
        for (int i = tid; i < 512; i += 256)
            sb[i] = sa[i] + ((i >= off) ? sa[i - off] : 0);
        __syncthreads();
        int* t = sa; sa = sb; sb = t;
    }
    for (int i = tid; i < NCHUNK; i += 256) {
        int excl = sa[i] - s_hist[i];
        s_offs[i] = excl;
        s_cur[i]  = excl;
    }
    __syncthreads();
    for (int k = 0; k < nloc; k++) {
        int c = pk[k] >> 23;
        int pos = atomicAdd(&s_cur[c], 1);
        s_sorted[pos] = pk[k];
    }
    __syncthreads();
    for (int c = tid; c < NCHUNK; c += 256) {
        int n = s_hist[c];
        s_gb[c] = n ? atomicAdd(&gcur[c], n) : 0;
    }
    __syncthreads();
    for (int i = tid; i < cnt; i += 256) {
        uint v = s_sorted[i];
        int c = v >> 23;
        int li = i - s_offs[c];
        bucket[(size_t)c * CHCAP + s_gb[c] + li] = v;
    }
}

// phase B: one block per chunk — inline base scan + per-row hist/scan -> rowPtr + dense fill.
__global__ __launch_bounds__(256) void fillB_kernel(
    const uint* __restrict__ bucket, const int* __restrict__ gcur,
    int* __restrict__ rowPtr, int* __restrict__ csr_src)
{
    __shared__ int s_hist[128];
    __shared__ int s_excl[128];
    __shared__ int s_cur[128];
    __shared__ int s_ws[4];
    __shared__ int s_base;
    const int c = blockIdx.x;
    const int tid = threadIdx.x;
    const int cnt = gcur[c];
    const int row0 = c * 128;

    int part = 0;
    for (int i = tid; i < c; i += 256) part += gcur[i];
    #pragma unroll
    for (int off = 32; off >= 1; off >>= 1) part += __shfl_down(part, off, 64);
    if ((tid & 63) == 0) s_ws[tid >> 6] = part;
    if (tid < 128) s_hist[tid] = 0;
    __syncthreads();
    if (tid == 0) s_base = s_ws[0] + s_ws[1] + s_ws[2] + s_ws[3];
    __syncthreads();
    const int base = s_base;
    if (tid == 0 && c == NCHUNK - 1) rowPtr[NN] = base + cnt;

    for (int i = tid; i < cnt; i += 256) {
        uint v = bucket[(size_t)c * CHCAP + i];
        atomicAdd(&s_hist[(v >> 16) & 127], 1);
    }
    __syncthreads();
    if (tid < 128) {
        int lane = tid & 63;
        int v = s_hist[tid];
        int incl = v;
        #pragma unroll
        for (int off = 1; off < 64; off <<= 1) {
            int t = __shfl_up(incl, off, 64);
            if (lane >= off) incl += t;
        }
        s_excl[tid] = incl - v;
    }
    __syncthreads();
    if (tid < 128) {
        int excl = s_excl[tid];
        if (tid >= 64) excl += s_excl[63] + s_hist[63];
        s_cur[tid] = excl;
        int row = row0 + tid;
        if (row < NN) rowPtr[row] = base + excl;
    }
    __syncthreads();
    for (int i = tid; i < cnt; i += 256) {
        uint v = bucket[(size_t)c * CHCAP + i];
        int dl  = (v >> 16) & 127;
        int src = v & 0xFFFFu;
        int ofs = atomicAdd(&s_cur[dl], 1);
        csr_src[base + ofs] = src;
    }
}

// ======== proj: y = W_a^T * z, z = BNReLU(h_in) [APPLY] or cvt(x) [layer 1] ========
// Side job: blocks 0..7 pre-pack this layer's wb into fp16 gather layout (wbh).
template<int FIN, bool APPLY>
__global__ __launch_bounds__(256, 4) void proj_kernel(
    const void* __restrict__ in_v,
    const float* __restrict__ stats_in, const float* __restrict__ g_in,
    const float* __restrict__ be_in,
    const float* __restrict__ wa,
    const float* __restrict__ wb_src, _Float16* __restrict__ wbh_out,
    ushort* __restrict__ y_out)
{
    constexpr int KC = FIN / 32;
    __shared__ __align__(16) _Float16 s_B[FIN * 64];
    __shared__ __align__(16) _Float16 s_Y[4][1024];

    const int tid = threadIdx.x, w = tid >> 6, lane = tid & 63;
    const int q = lane >> 4, mm = lane & 15;

    if (blockIdx.x < 8) {
        for (int t = tid; t < 512; t += 256) {
            int i = blockIdx.x * 512 + t;
            int j = i & 7, l = (i >> 3) & 63, tt = i >> 9;
            int kc = tt >> 2, nt = tt & 3;
            int k = kc * 32 + (l >> 4) * 8 + j;
            int n = nt * 16 + (l & 15);
            wbh_out[i] = (_Float16)wb_src[k * 64 + n];
        }
    }

    for (int i = tid; i < FIN * 64; i += 256) {
        int j = i & 7, l = (i >> 3) & 63, t = i >> 9;
        int kc = t >> 2, nt = t & 3;
        int k = kc * 32 + (l >> 4) * 8 + j;
        int n = nt * 16 + (l & 15);
        s_B[i] = (_Float16)wa[k * 64 + n];
    }

    float scv[2][8], shv[2][8];
    if (APPLY) {
        #pragma unroll
        for (int kc = 0; kc < 2; kc++)
            #pragma unroll
            for (int j = 0; j < 8; j++) {
                int c = kc * 32 + q * 8 + j;
                float s0 = 0.f, s1 = 0.f;
                #pragma unroll
                for (int r = 0; r < NREP; r++) {
                    s0 += stats_in[r * 128 + c];
                    s1 += stats_in[r * 128 + 64 + c];
                }
                float mean = s0 * (1.0f / NN);
                float var  = s1 * (1.0f / NN) - mean * mean;
                float rstd = rsqrtf(var + BN_EPS);
                float s    = rstd * g_in[c];
                scv[kc][j] = s;
                shv[kc][j] = be_in[c] - mean * s;
            }
    }
    __syncthreads();

    int g = blockIdx.x * 4 + w;
    if (g >= NGROUP) return;
    const int row = g * 16 + mm;

    half8 af[KC];
    if (FIN == 128) {
        const float* xin = (const float*)in_v;
        #pragma unroll
        for (int kc = 0; kc < KC; kc++) {
            const float* p = xin + (size_t)row * 128 + kc * 32 + q * 8;
            float4 a = *(const float4*)p;
            float4 b = *(const float4*)(p + 4);
            half8 hv;
            hv[0] = (_Float16)a.x; hv[1] = (_Float16)a.y;
            hv[2] = (_Float16)a.z; hv[3] = (_Float16)a.w;
            hv[4] = (_Float16)b.x; hv[5] = (_Float16)b.y;
            hv[6] = (_Float16)b.z; hv[7] = (_Float16)b.w;
            af[kc] = hv;
        }
    } else {
        const ushort* hin = (const ushort*)in_v;
        #pragma unroll
        for (int kc = 0; kc < KC; kc++) {
            uint4 vv = *(const uint4*)(hin + (size_t)row * 64 + kc * 32 + q * 8);
            float f[8]; unpack8(vv, f);
            half8 hv;
            #pragma unroll
            for (int j = 0; j < 8; j++) {
                float z = APPLY ? fmaxf(fmaf(f[j], scv[kc][j], shv[kc][j]), 0.0f) : f[j];
                hv[j] = (_Float16)z;
            }
            af[kc] = hv;
        }
    }

    floatx4 acc[4] = {};
    #pragma unroll
    for (int nt = 0; nt < 4; nt++)
        #pragma unroll
        for (int kc = 0; kc < KC; kc++) {
            half8 bf = *(const half8*)(s_B + ((size_t)(kc * 4 + nt) * 64 + lane) * 8);
            acc[nt] = __builtin_amdgcn_mfma_f32_16x16x32_f16(af[kc], bf, acc[nt], 0, 0, 0);
        }

    _Float16* s_Yw = &s_Y[w][0];
    #pragma unroll
    for (int nt = 0; nt < 4; nt++)
        #pragma unroll
        for (int r = 0; r < 4; r++)
            s_Yw[(q * 4 + r) * 64 + nt * 16 + mm] = (_Float16)acc[nt][r];
    half8 t0 = *(const half8*)(s_Yw + lane * 8);
    half8 t1 = *(const half8*)(s_Yw + 512 + lane * 8);
    half8* dst = (half8*)((_Float16*)y_out + (size_t)g * 1024);
    dst[lane] = t0;
    dst[64 + lane] = t1;
}

// ======== gather (R0 decomposition, width-2 inner loop): 391 blocks, 512 thr,
// 1 wave owns one 16-row group, 4-row batches. Per iteration each lane issues TWO
// independent csr loads (e, e+8) then TWO independent y4 loads per row -> 8 y4 loads
// in flight, 16 edges per lane-group per chain step (R0: 8). No cross-iteration value
// buffer (R5's spill source). Bounded loop (cap >> max degree) guarantees termination. ========
__global__ __launch_bounds__(512, 4) void gin_gather_kernel(
    const ushort* __restrict__ y,
    const int* __restrict__ rowPtr, const int* __restrict__ csr_src,
    const float* __restrict__ eps_p, const _Float16* __restrict__ wbh,
    const float* __restrict__ ba, const float* __restrict__ bb,
    ushort* __restrict__ h_out, float* __restrict__ stats_out)
{
    __shared__ __align__(16) _Float16 s_B2[64 * 64];
    __shared__ __align__(16) _Float16 s_A[8][1024];
    __shared__ float s_red[8][64];

    const int tid = threadIdx.x, w = tid >> 6, lane = tid & 63;
    const int cc = lane & 7, gph = lane >> 3;
    const int q = lane >> 4, mm = lane & 15;

    // coalesced B2 stage: 512 x 16B from pre-packed wbh
    ((half8*)s_B2)[tid] = ((const half8*)wbh)[tid];

    const float eps1 = 1.0f + eps_p[0];
    __syncthreads();

    float bn_s[4] = {0.f, 0.f, 0.f, 0.f};
    float bn_q[4] = {0.f, 0.f, 0.f, 0.f};
    const uint4* y4 = (const uint4*)y;
    const int g = blockIdx.x * 8 + w;

    if (g < NGROUP) {
        const int row0 = g * 16;
        _Float16* s_Aw = &s_A[w][0];

        for (int m = 0; m < 16; m += 4) {
            int e[4], en[4];
            uint4 pk[4];
            #pragma unroll
            for (int i = 0; i < 4; i++) {
                int row = row0 + m + i;
                e[i] = rowPtr[row] + gph;
                en[i] = rowPtr[row + 1];
                pk[i].x = pk[i].y = pk[i].z = pk[i].w = 0u;
            }

            // cap 512 iters = 65536 edges/row >> max degree (~60); break is the real exit.
            for (int it = 0; it < 512; ++it) {
                int i0[4], i1[4];
                #pragma unroll
                for (int i = 0; i < 4; i++) i0[i] = (e[i] < en[i]) ? csr_src[e[i]] : -1;
                #pragma unroll
                for (int i = 0; i < 4; i++) i1[i] = (e[i] + 8 < en[i]) ? csr_src[e[i] + 8] : -1;
                int mx0 = max(max(i0[0], i0[1]), max(i0[2], i0[3]));
                int mx1 = max(max(i1[0], i1[1]), max(i1[2], i1[3]));
                if (max(mx0, mx1) < 0) break;
                uint4 u0[4], u1[4];
                #pragma unroll
                for (int i = 0; i < 4; i++) if (i0[i] >= 0) u0[i] = y4[(size_t)i0[i] * 8 + cc];
                #pragma unroll
                for (int i = 0; i < 4; i++) if (i1[i] >= 0) u1[i] = y4[(size_t)i1[i] * 8 + cc];
                #pragma unroll
                for (int i = 0; i < 4; i++) {
                    if (i0[i] >= 0) pkadd4(pk[i], u0[i]);
                    if (i1[i] >= 0) pkadd4(pk[i], u1[i]);
                    e[i] += 16;
                }
            }

            // Batched flush: all 4 rows interleaved (4x the shfl-chain ILP of per-row).
            float a[4][8];
            #pragma unroll
            for (int i = 0; i < 4; i++) unpack8(pk[i], a[i]);
            if (gph == 0) {
                #pragma unroll
                for (int i = 0; i < 4; i++) {
                    uint4 sv = y4[(size_t)(row0 + m + i) * 8 + cc];
                    float f[8]; unpack8(sv, f);
                    #pragma unroll
                    for (int j = 0; j < 8; j++) a[i][j] = fmaf(eps1, f[j], a[i][j]);
                }
            }
            #pragma unroll
            for (int off = 8; off < 64; off <<= 1)
                #pragma unroll
                for (int i = 0; i < 4; i++)
                    #pragma unroll
                    for (int j = 0; j < 8; j++)
                        a[i][j] += __shfl_xor(a[i][j], off, 64);
            if (gph == 0) {
                #pragma unroll
                for (int i = 0; i < 4; i++) {
                    half8 hv;
                    #pragma unroll
                    for (int j = 0; j < 8; j++)
                        hv[j] = (_Float16)fmaxf(a[i][j] + ba[8 * cc + j], 0.0f);
                    int slot = (cc >> 2) * 64 + (cc & 3) * 16 + (m + i);
                    *(half8*)(s_Aw + (size_t)aswz(slot) * 8) = hv;
                }
            }
        }

        float bbv[4];
        #pragma unroll
        for (int nt = 0; nt < 4; nt++) bbv[nt] = bb[nt * 16 + mm];

        half8 af2[2];
        #pragma unroll
        for (int kc = 0; kc < 2; kc++)
            af2[kc] = *(const half8*)(s_Aw + (size_t)aswz(kc * 64 + lane) * 8);
        floatx4 acc2[4] = {};
        #pragma unroll
        for (int nt = 0; nt < 4; nt++)
            #pragma unroll
            for (int kc = 0; kc < 2; kc++) {
                half8 bf = *(const half8*)(s_B2 + ((size_t)(kc * 4 + nt) * 64 + lane) * 8);
                acc2[nt] = __builtin_amdgcn_mfma_f32_16x16x32_f16(af2[kc], bf, acc2[nt], 0, 0, 0);
            }

        #pragma unroll
        for (int nt = 0; nt < 4; nt++)
            #pragma unroll
            for (int r = 0; r < 4; r++) {
                float val = fmaxf(acc2[nt][r] + bbv[nt], 0.0f);
                bn_s[nt] += val;
                bn_q[nt] += val * val;
                s_Aw[(q * 4 + r) * 64 + nt * 16 + mm] = (_Float16)val;
            }
        half8 t0 = *(const half8*)(s_Aw + lane * 8);
        half8 t1 = *(const half8*)(s_Aw + 512 + lane * 8);
        half8* dst = (half8*)((_Float16*)h_out + (size_t)row0 * 64);
        dst[lane] = t0;
        dst[64 + lane] = t1;
    }

    #pragma unroll
    for (int nt = 0; nt < 4; nt++) {
        bn_s[nt] += __shfl_xor(bn_s[nt], 16, 64);
        bn_s[nt] += __shfl_xor(bn_s[nt], 32, 64);
        bn_q[nt] += __shfl_xor(bn_q[nt], 16, 64);
        bn_q[nt] += __shfl_xor(bn_q[nt], 32, 64);
    }
    __syncthreads();
    if (lane < 16) {
        #pragma unroll
        for (int nt = 0; nt < 4; nt++) s_red[w][nt * 16 + lane] = bn_s[nt];
    }
    __syncthreads();
    if (w == 0) {
        float s = 0;
        #pragma unroll
        for (int j = 0; j < 8; j++) s += s_red[j][lane];
        atomicAdd(&stats_out[(size_t)(blockIdx.x & (NREP - 1)) * 128 + lane], s);
    }
    __syncthreads();
    if (lane < 16) {
        #pragma unroll
        for (int nt = 0; nt < 4; nt++) s_red[w][nt * 16 + lane] = bn_q[nt];
    }
    __syncthreads();
    if (w == 0) {
        float s = 0;
        #pragma unroll
        for (int j = 0; j < 8; j++) s += s_red[j][lane];
        atomicAdd(&stats_out[(size_t)(blockIdx.x & (NREP - 1)) * 128 + 64 + lane], s);
    }
}

// ---------------- final: BN+ReLU of layer 3 (fp16 h), then (N,64)@(64,10)+b ----------------
__global__ __launch_bounds__(256) void final_linear_kernel(
    const ushort* __restrict__ h, const float* __restrict__ stats,
    const float* __restrict__ g, const float* __restrict__ be,
    const float* __restrict__ w, const float* __restrict__ b,
    float* __restrict__ out)
{
    __shared__ float s_w[640];
    __shared__ float s_b[10];
    __shared__ float s_scale[64];
    __shared__ float s_shift[64];
    for (int i = threadIdx.x; i < 640; i += 256) s_w[i] = w[i];
    if (threadIdx.x < 10) s_b[threadIdx.x] = b[threadIdx.x];
    if (threadIdx.x < 64) {
        int c = threadIdx.x;
        float s0 = 0.f, s1 = 0.f;
        #pragma unroll
        for (int r = 0; r < NREP; r++) {
            s0 += stats[r * 128 + c];
            s1 += stats[r * 128 + 64 + c];
        }
        float mean = s0 * (1.0f / NN);
        float var  = s1 * (1.0f / NN) - mean * mean;
        float rstd = rsqrtf(var + BN_EPS);
        float s    = rstd * g[c];
        s_scale[c] = s;
        s_shift[c] = be[c] - mean * s;
    }
    __syncthreads();
    int row = blockIdx.x * 256 + threadIdx.x;
    if (row >= NN) return;
    float acc[10];
    #pragma unroll
    for (int c = 0; c < 10; c++) acc[c] = s_b[c];
    const uint4* hr = (const uint4*)(h + (size_t)row * 64);
    #pragma unroll
    for (int ch = 0; ch < 8; ch++) {
        uint4 v = hr[ch];
        float f[8]; unpack8(v, f);
        #pragma unroll
        for (int j = 0; j < 8; j++) {
            int k = ch * 8 + j;
            float val = fmaxf(fmaf(f[j], s_scale[k], s_shift[k]), 0.0f);
            #pragma unroll
            for (int c = 0; c < 10; c++) acc[c] = fmaf(val, s_w[k * 10 + c], acc[c]);
        }
    }
    #pragma unroll
    for (int c = 0; c < 10; c++) out[row * 10 + c] = acc[c];
}

extern "C" void kernel_launch(void* const* d_in, const int* in_sizes, int n_in,
                              void* d_out, int out_size, void* d_ws, size_t ws_size,
                              hipStream_t stream)
{
    const float* x  = (const float*)d_in[0];
    const int*   ei = (const int*)d_in[1];
    const int E = in_sizes[1] / 2;

    const float* eps[3]; const float* wa[3]; const float* ba[3];
    const float* wb[3];  const float* bb[3]; const float* g[3]; const float* be[3];
    for (int i = 0; i < 3; i++) {
        int base = 2 + 7 * i;
        eps[i] = (const float*)d_in[base + 0];
        wa[i]  = (const float*)d_in[base + 1];
        ba[i]  = (const float*)d_in[base + 2];
        wb[i]  = (const float*)d_in[base + 3];
        bb[i]  = (const float*)d_in[base + 4];
        g[i]   = (const float*)d_in[base + 5];
        be[i]  = (const float*)d_in[base + 6];
    }
    const float* lin_w = (const float*)d_in[23];
    const float* lin_b = (const float*)d_in[24];
    float* out = (float*)d_out;

    // workspace layout: gcur and stats adjacent -> single zeroing memset
    char*  base   = (char*)d_ws;
    int*   gcur   = (int*)base;               // 512 ints
    float* stats  = (float*)(gcur + 512);     // 3 layers x NREP x 128 floats
    int*   rowPtr = (int*)(stats + 3 * NREP * 128);  // NN+1
    uint*  bucket = (uint*)(rowPtr + NN + 1); // NCHUNK*CHCAP
    int*   csrsrc = (int*)(bucket + (size_t)NCHUNK * CHCAP);  // E
    size_t hoff   = (char*)(csrsrc + E) - base;
    _Float16* wbh = (_Float16*)(base + ((hoff + 15) & ~(size_t)15));  // 4096
    ushort* yb    = (ushort*)(wbh + 4096);    // NN*64
    ushort* hA    = yb + (size_t)NN * 64;     // NN*64
    ushort* hB    = hA + (size_t)NN * 64;     // NN*64

    // ---- CSR build (bucketed, R0 config) ----
    hipMemsetAsync(gcur, 0, (512 + 3 * NREP * 128) * sizeof(int), stream);
    sortA_kernel<<<(E + SLAB - 1) / SLAB, 256, 0, stream>>>(ei, gcur, bucket, E);
    fillB_kernel<<<NCHUNK, 256, 0, stream>>>(bucket, gcur, rowPtr, csrsrc);

    const int PB = (NGROUP + 3) / 4;   // 782 proj blocks
    const int GB = (NGROUP + 7) / 8;   // 391 gather blocks (1 wave per group)

    // ---- layer 1: proj x (fp32,128) -> y; fused gather+MLP ----
    proj_kernel<128, false><<<PB, 256, 0, stream>>>(
        x, nullptr, nullptr, nullptr, wa[0], wb[0], wbh, yb);
    gin_gather_kernel<<<GB, 512, 0, stream>>>(
        yb, rowPtr, csrsrc, eps[0], wbh, ba[0], bb[0], hA, stats);
    // ---- layer 2 ----
    proj_kernel<64, true><<<PB, 256, 0, stream>>>(
        hA, stats, g[0], be[0], wa[1], wb[1], wbh, yb);
    gin_gather_kernel<<<GB, 512, 0, stream>>>(
        yb, rowPtr, csrsrc, eps[1], wbh, ba[1], bb[1], hB, stats + NREP * 128);
    // ---- layer 3 ----
    proj_kernel<64, true><<<PB, 256, 0, stream>>>(
        hB, stats + NREP * 128, g[1], be[1], wa[2], wb[2], wbh, yb);
    gin_gather_kernel<<<GB, 512, 0, stream>>>(
        yb, rowPtr, csrsrc, eps[2], wbh, ba[2], bb[2], hA, stats + 2 * NREP * 128);
    // ---- final ----
    final_linear_kernel<<<(NN + 255) / 256, 256, 0, stream>>>(
        hA, stats + 2 * NREP * 128, g[2], be[2], lin_w, lin_b, out);
}